// Round 1
// baseline (3162.233 us; speedup 1.0000x reference)
//
#include <hip/hip_runtime.h>
#include <hip/hip_bf16.h>

// Problem constants
#define BTOT 32768
#define NPOS 56            // 7*8
#define CNT1 1835008.0f    // BTOT*NPOS

// ws float offsets
#define WS_SUM1 0
#define WS_SSQ1 16
#define WS_SUM2 32
#define WS_SSQ2 64
#define WS_A1   96
#define WS_D1   112
#define WS_A2   128
#define WS_D2   160
#define WS_W2T  192
#define WS_FC1T 4800
#define WS_MUT  463552
#define WS_LVT  496320
// total = 529088 floats (~2.02 MB)

// ---------------- K0: pack/transpose weights into ws ----------------
__global__ __launch_bounds__(256) void k_pack(const float* __restrict__ w2,
    const float* __restrict__ fw, const float* __restrict__ muw,
    const float* __restrict__ lvw, float* __restrict__ ws) {
  int t = blockIdx.x * 256 + threadIdx.x;
  int stride = gridDim.x * 256;
  for (int d = t; d < 4608; d += stride) {       // conv2 w: [c2][c1][3][3] -> [(c1*9+k)][c2]
    int c2 = d / 144, rr = d % 144;
    ws[WS_W2T + rr * 32 + c2] = w2[d];
  }
  for (int d = t; d < 458752; d += stride) {     // fc1 w: [j][idx] -> [idx][j]
    int idx = d >> 8, j = d & 255;
    ws[WS_FC1T + d] = fw[j * 1792 + idx];
  }
  for (int d = t; d < 32768; d += stride) {      // heads: [o][kk] -> [kk][o]
    int kk = d >> 7, o = d & 127;
    ws[WS_MUT + d] = muw[o * 256 + kk];
    ws[WS_LVT + d] = lvw[o * 256 + kk];
  }
}

// ---------------- K1: conv1 batch stats ----------------
__global__ __launch_bounds__(256) void k_stats1(const float* __restrict__ x,
    const float* __restrict__ w1, const float* __restrict__ b1, float* __restrict__ ws) {
  __shared__ float xbs[4][96];
  int tid = threadIdx.x, wv = tid >> 6, lane = tid & 63;
  int c = lane >> 2, nsub = lane & 3;
  float wr[9];
#pragma unroll
  for (int k = 0; k < 9; ++k) wr[k] = w1[c * 9 + k];
  float bias = b1[c];
  float s = 0.f, ss = 0.f;
  float* xsp = xbs[wv];
  for (int it = 0; it < 16; ++it) {
    int b = blockIdx.x * 64 + wv * 16 + it;
    for (int i = lane; i < 96; i += 64) xsp[i] = 0.f;
    __syncthreads();
    if (lane < 56) xsp[((lane >> 3) + 1) * 10 + (lane & 7) + 1] = x[(size_t)b * NPOS + lane];
    __syncthreads();
#pragma unroll
    for (int i = 0; i < 14; ++i) {
      int n = nsub * 14 + i;
      int base = (n >> 3) * 10 + (n & 7);
      float acc = bias;
#pragma unroll
      for (int ky = 0; ky < 3; ++ky)
#pragma unroll
        for (int kx = 0; kx < 3; ++kx)
          acc += wr[ky * 3 + kx] * xsp[base + ky * 10 + kx];
      s += acc; ss += acc * acc;
    }
    __syncthreads();
  }
  s += __shfl_xor(s, 1);  s += __shfl_xor(s, 2);
  ss += __shfl_xor(ss, 1); ss += __shfl_xor(ss, 2);
  if ((lane & 3) == 0) {
    atomicAdd(&ws[WS_SUM1 + c], s);
    atomicAdd(&ws[WS_SSQ1 + c], ss);
  }
}

// ---------------- K2/K4: finalize BN stats -> folded scale/shift ----------------
__global__ void k_finalize(const float* __restrict__ bnw, const float* __restrict__ bnb,
    const float* __restrict__ cb, float* __restrict__ ws,
    int nc, int so, int qo, int ao, int dof) {
  int c = threadIdx.x;
  if (c < nc) {
    float mean = ws[so + c] / CNT1;
    float var = ws[qo + c] / CNT1 - mean * mean;
    float a = bnw[c] * rsqrtf(var + 1e-5f);
    ws[ao + c] = a;
    ws[dof + c] = bnb[c] + a * (cb[c] - mean);   // conv bias folded in
  }
}

// ---------------- K3: conv2 batch stats (recompute conv1+bn1) ----------------
__global__ __launch_bounds__(256) void k_stats2(const float* __restrict__ x,
    const float* __restrict__ w1, const float* __restrict__ cb2, float* __restrict__ ws) {
  __shared__ float w2t_s[4608];
  __shared__ __align__(16) float h1ps[4][1440];
  __shared__ float xbs[4][96];
  int tid = threadIdx.x, wv = tid >> 6, lane = tid & 63;
  for (int i = tid; i < 4608; i += 256) w2t_s[i] = ws[WS_W2T + i];
  int c1l = lane >> 2, nsub = lane & 3;
  float wr[9];
#pragma unroll
  for (int k = 0; k < 9; ++k) wr[k] = w1[c1l * 9 + k];
  float a1 = ws[WS_A1 + c1l], d1 = ws[WS_D1 + c1l];
  int c2a = lane & 15, half = lane >> 4;
  float b2a = cb2[c2a], b2b = cb2[c2a + 16];
  int pos[14];
#pragma unroll
  for (int j = 0; j < 14; ++j) { int n = half * 14 + j; pos[j] = (n >> 3) * 10 + (n & 7); }
  float sA = 0.f, ssA = 0.f, sB = 0.f, ssB = 0.f;
  float* xsp = xbs[wv]; float* h1p = h1ps[wv];
  __syncthreads();
  for (int it = 0; it < 16; ++it) {
    int b = blockIdx.x * 64 + wv * 16 + it;
    for (int i = lane; i < 96; i += 64) xsp[i] = 0.f;
    for (int i = lane; i < 1440; i += 64) h1p[i] = 0.f;
    __syncthreads();
    if (lane < 56) xsp[((lane >> 3) + 1) * 10 + (lane & 7) + 1] = x[(size_t)b * NPOS + lane];
    __syncthreads();
#pragma unroll
    for (int i = 0; i < 14; ++i) {
      int n = nsub * 14 + i;
      int base = (n >> 3) * 10 + (n & 7);
      float acc = 0.f;
#pragma unroll
      for (int ky = 0; ky < 3; ++ky)
#pragma unroll
        for (int kx = 0; kx < 3; ++kx)
          acc += wr[ky * 3 + kx] * xsp[base + ky * 10 + kx];
      h1p[c1l * 90 + base + 11] = fmaxf(acc * a1 + d1, 0.f);
    }
    __syncthreads();
    float accA[14], accB[14];
#pragma unroll
    for (int j = 0; j < 14; ++j) { accA[j] = b2a; accB[j] = b2b; }
    for (int c1 = 0; c1 < 16; ++c1) {
      float wA[9], wB[9];
#pragma unroll
      for (int k = 0; k < 9; ++k) {
        wA[k] = w2t_s[(c1 * 9 + k) * 32 + c2a];
        wB[k] = w2t_s[(c1 * 9 + k) * 32 + c2a + 16];
      }
      const float* hp = &h1p[c1 * 90];
#pragma unroll
      for (int j = 0; j < 14; ++j) {
#pragma unroll
        for (int k9 = 0; k9 < 9; ++k9) {
          float hv = hp[pos[j] + (k9 / 3) * 10 + (k9 % 3)];
          accA[j] += wA[k9] * hv; accB[j] += wB[k9] * hv;
        }
      }
    }
#pragma unroll
    for (int j = 0; j < 14; ++j) {
      sA += accA[j]; ssA += accA[j] * accA[j];
      sB += accB[j]; ssB += accB[j] * accB[j];
    }
    __syncthreads();
  }
  sA += __shfl_xor(sA, 16); sA += __shfl_xor(sA, 32);
  ssA += __shfl_xor(ssA, 16); ssA += __shfl_xor(ssA, 32);
  sB += __shfl_xor(sB, 16); sB += __shfl_xor(sB, 32);
  ssB += __shfl_xor(ssB, 16); ssB += __shfl_xor(ssB, 32);
  if (lane < 16) {
    atomicAdd(&ws[WS_SUM2 + lane], sA);
    atomicAdd(&ws[WS_SSQ2 + lane], ssA);
    atomicAdd(&ws[WS_SUM2 + 16 + lane], sB);
    atomicAdd(&ws[WS_SSQ2 + 16 + lane], ssB);
  }
}

// ---------------- K5: main fused pass ----------------
__global__ __launch_bounds__(256) void k_main(
    const float* __restrict__ x, const float* __restrict__ w1,
    const float* __restrict__ qw, const float* __restrict__ qb_,
    const float* __restrict__ kw, const float* __restrict__ kb_,
    const float* __restrict__ vw, const float* __restrict__ vb_,
    const float* __restrict__ gp, const float* __restrict__ fc1b,
    const float* __restrict__ mub, const float* __restrict__ lvb,
    const float* __restrict__ ws, float* __restrict__ out) {
  __shared__ __align__(16) float hstore[16][1792];   // 112 KB: post-attention h, fp32
  __shared__ __align__(16) float scratch[4][1440];   // h1 padded; later q/k; later f
  __shared__ float w2t_s[4608];
  int tid = threadIdx.x, wv = tid >> 6, lane = tid & 63;
  for (int i = tid; i < 4608; i += 256) w2t_s[i] = ws[WS_W2T + i];
  int c1l = lane >> 2, nsub = lane & 3;
  float wr[9];
#pragma unroll
  for (int k = 0; k < 9; ++k) wr[k] = w1[c1l * 9 + k];
  float a1 = ws[WS_A1 + c1l], d1 = ws[WS_D1 + c1l];
  int c2a = lane & 15, half = lane >> 4;
  float a2A = ws[WS_A2 + c2a], d2A = ws[WS_D2 + c2a];
  float a2B = ws[WS_A2 + c2a + 16], d2B = ws[WS_D2 + c2a + 16];
  int pos[14];
#pragma unroll
  for (int j = 0; j < 14; ++j) { int n = half * 14 + j; pos[j] = (n >> 3) * 10 + (n & 7); }
  float gamma = gp[0];
  int b0 = blockIdx.x * 16;
  __syncthreads();

  for (int r = 0; r < 4; ++r) {
    int sl = wv * 4 + r;
    int b = b0 + sl;
    float* h2 = hstore[sl];
    float* h1p = scratch[wv];
    float* xsp = h2;   // x staged in first 90 floats of h2 (dead until conv2)
    for (int i = lane; i < 96; i += 64) xsp[i] = 0.f;
    for (int i = lane; i < 1440; i += 64) h1p[i] = 0.f;
    __syncthreads();
    if (lane < 56) xsp[((lane >> 3) + 1) * 10 + (lane & 7) + 1] = x[(size_t)b * NPOS + lane];
    __syncthreads();
    // conv1 + bn1 + relu
#pragma unroll
    for (int i = 0; i < 14; ++i) {
      int n = nsub * 14 + i;
      int base = (n >> 3) * 10 + (n & 7);
      float acc = 0.f;
#pragma unroll
      for (int ky = 0; ky < 3; ++ky)
#pragma unroll
        for (int kx = 0; kx < 3; ++kx)
          acc += wr[ky * 3 + kx] * xsp[base + ky * 10 + kx];
      h1p[c1l * 90 + base + 11] = fmaxf(acc * a1 + d1, 0.f);
    }
    __syncthreads();
    // conv2 + bn2 + relu -> h2
    {
      float accA[14], accB[14];
#pragma unroll
      for (int j = 0; j < 14; ++j) { accA[j] = 0.f; accB[j] = 0.f; }
      for (int c1 = 0; c1 < 16; ++c1) {
        float wA[9], wB[9];
#pragma unroll
        for (int k = 0; k < 9; ++k) {
          wA[k] = w2t_s[(c1 * 9 + k) * 32 + c2a];
          wB[k] = w2t_s[(c1 * 9 + k) * 32 + c2a + 16];
        }
        const float* hp = &h1p[c1 * 90];
#pragma unroll
        for (int j = 0; j < 14; ++j) {
#pragma unroll
          for (int k9 = 0; k9 < 9; ++k9) {
            float hv = hp[pos[j] + (k9 / 3) * 10 + (k9 % 3)];
            accA[j] += wA[k9] * hv; accB[j] += wB[k9] * hv;
          }
        }
      }
#pragma unroll
      for (int j = 0; j < 14; ++j) {
        int n = half * 14 + j;
        h2[c2a * 56 + n] = fmaxf(accA[j] * a2A + d2A, 0.f);
        h2[(c2a + 16) * 56 + n] = fmaxf(accB[j] * a2B + d2B, 0.f);
      }
    }
    __syncthreads();
    // q,k projections (h1p region reused)
    float* qbuf = scratch[wv];
    float* kbuf = scratch[wv] + 224;
    if (lane < 56) {
      float qa[4], ka[4];
#pragma unroll
      for (int o = 0; o < 4; ++o) { qa[o] = qb_[o]; ka[o] = kb_[o]; }
#pragma unroll
      for (int cc = 0; cc < 32; ++cc) {
        float hv = h2[cc * 56 + lane];
#pragma unroll
        for (int o = 0; o < 4; ++o) {
          qa[o] += qw[o * 32 + cc] * hv;
          ka[o] += kw[o * 32 + cc] * hv;
        }
      }
#pragma unroll
      for (int o = 0; o < 4; ++o) { qbuf[o * 56 + lane] = qa[o]; kbuf[o * 56 + lane] = ka[o]; }
    }
    __syncthreads();
    // softmax(q^T k) fused with t = P @ h2^T   (v never materialized)
    float t[32];
    float inv = 0.f;
    if (lane < 56) {
      float q0 = qbuf[lane], q1 = qbuf[56 + lane], q2 = qbuf[112 + lane], q3 = qbuf[168 + lane];
      float m = -1e30f;
      for (int j = 0; j < 56; ++j) {
        float s = q0 * kbuf[j] + q1 * kbuf[56 + j] + q2 * kbuf[112 + j] + q3 * kbuf[168 + j];
        m = fmaxf(m, s);
      }
#pragma unroll
      for (int cc = 0; cc < 32; ++cc) t[cc] = 0.f;
      float denom = 0.f;
      for (int j = 0; j < 56; ++j) {
        float s = q0 * kbuf[j] + q1 * kbuf[56 + j] + q2 * kbuf[112 + j] + q3 * kbuf[168 + j];
        float p = __expf(s - m);
        denom += p;
#pragma unroll
        for (int cc = 0; cc < 32; ++cc) t[cc] += p * h2[cc * 56 + j];
      }
      inv = 1.f / denom;
    }
    __syncthreads();
    // out = vb + inv * (vw @ t); residual update (column-exclusive per lane)
    if (lane < 56) {
#pragma unroll
      for (int c = 0; c < 32; ++c) {
        float acc = 0.f;
#pragma unroll
        for (int cc = 0; cc < 32; ++cc) acc += vw[c * 32 + cc] * t[cc];
        float ov = vb_[c] + inv * acc;
        h2[c * 56 + lane] = gamma * ov + h2[c * 56 + lane];
      }
    }
    __syncthreads();
  }

  // -------- phase 2: fc1 GEMM, thread owns column j, 16 sample accumulators --------
  float facc[16];
#pragma unroll
  for (int s = 0; s < 16; ++s) facc[s] = 0.f;
  {
    const float* wT = ws + WS_FC1T;
    int j = tid;
    for (int kk = 0; kk < 1792; kk += 4) {
      float w0 = wT[(kk + 0) * 256 + j];
      float w1v = wT[(kk + 1) * 256 + j];
      float w2v = wT[(kk + 2) * 256 + j];
      float w3v = wT[(kk + 3) * 256 + j];
#pragma unroll
      for (int s = 0; s < 16; ++s) {
        const float4 hv = *reinterpret_cast<const float4*>(&hstore[s][kk]);
        facc[s] += hv.x * w0 + hv.y * w1v + hv.z * w2v + hv.w * w3v;
      }
    }
  }
  float* fs = &scratch[0][0];   // 16*256 floats
  {
    int j = tid;
    float bj = fc1b[j];
#pragma unroll
    for (int s = 0; s < 16; ++s) fs[s * 256 + j] = fmaxf(facc[s] + bj, 0.f);
  }
  __syncthreads();
  // -------- phase 3: heads --------
  {
    int o = tid & 127, which = tid >> 7;
    const float* hT = ws + (which ? WS_LVT : WS_MUT);
    float hb = which ? lvb[o] : mub[o];
    float macc[16];
#pragma unroll
    for (int s = 0; s < 16; ++s) macc[s] = 0.f;
    for (int kk = 0; kk < 256; kk += 4) {
      float w0 = hT[(kk + 0) * 128 + o];
      float w1v = hT[(kk + 1) * 128 + o];
      float w2v = hT[(kk + 2) * 128 + o];
      float w3v = hT[(kk + 3) * 128 + o];
#pragma unroll
      for (int s = 0; s < 16; ++s) {
        const float4 fv = *reinterpret_cast<const float4*>(&fs[s * 256 + kk]);
        macc[s] += fv.x * w0 + fv.y * w1v + fv.z * w2v + fv.w * w3v;
      }
    }
    size_t obase = which ? (size_t)BTOT * 128 : 0;
#pragma unroll
    for (int s = 0; s < 16; ++s)
      out[obase + (size_t)(b0 + s) * 128 + o] = macc[s] + hb;
  }
}

extern "C" void kernel_launch(void* const* d_in, const int* in_sizes, int n_in,
                              void* d_out, int out_size, void* d_ws, size_t ws_size,
                              hipStream_t stream) {
  const float* x    = (const float*)d_in[0];
  const float* c1w  = (const float*)d_in[1];
  const float* c1b  = (const float*)d_in[2];
  const float* bn1w = (const float*)d_in[3];
  const float* bn1b = (const float*)d_in[4];
  const float* c2w  = (const float*)d_in[5];
  const float* c2b  = (const float*)d_in[6];
  const float* bn2w = (const float*)d_in[7];
  const float* bn2b = (const float*)d_in[8];
  const float* qw   = (const float*)d_in[9];
  const float* qb   = (const float*)d_in[10];
  const float* kw   = (const float*)d_in[11];
  const float* kb   = (const float*)d_in[12];
  const float* vw   = (const float*)d_in[13];
  const float* vb   = (const float*)d_in[14];
  const float* gm   = (const float*)d_in[15];
  const float* fw   = (const float*)d_in[16];
  const float* fb   = (const float*)d_in[17];
  const float* muw  = (const float*)d_in[18];
  const float* mub  = (const float*)d_in[19];
  const float* lvw  = (const float*)d_in[20];
  const float* lvb  = (const float*)d_in[21];
  float* ws = (float*)d_ws;
  float* out = (float*)d_out;

  hipMemsetAsync(d_ws, 0, 96 * sizeof(float), stream);
  hipLaunchKernelGGL(k_pack, dim3(512), dim3(256), 0, stream, c2w, fw, muw, lvw, ws);
  hipLaunchKernelGGL(k_stats1, dim3(512), dim3(256), 0, stream, x, c1w, c1b, ws);
  hipLaunchKernelGGL(k_finalize, dim3(1), dim3(64), 0, stream, bn1w, bn1b, c1b, ws,
                     16, WS_SUM1, WS_SSQ1, WS_A1, WS_D1);
  hipLaunchKernelGGL(k_stats2, dim3(512), dim3(256), 0, stream, x, c1w, c2b, ws);
  hipLaunchKernelGGL(k_finalize, dim3(1), dim3(64), 0, stream, bn2w, bn2b, c2b, ws,
                     32, WS_SUM2, WS_SSQ2, WS_A2, WS_D2);
  hipLaunchKernelGGL(k_main, dim3(2048), dim3(256), 0, stream, x, c1w,
                     qw, qb, kw, kb, vw, vb, gm, fb, mub, lvb, ws, out);
}

// Round 2
// 1288.763 us; speedup vs baseline: 2.4537x; 2.4537x over previous
//
#include <hip/hip_runtime.h>
#include <hip/hip_bf16.h>

// Problem constants
#define BTOT 32768
#define NPOS 56            // 7*8
#define CNT1 1835008.0f    // BTOT*NPOS

// ws float offsets
#define WS_SUM1 0
#define WS_SSQ1 16
#define WS_SUM2 32
#define WS_SSQ2 64
#define WS_A1   96
#define WS_D1   112
#define WS_A2   128
#define WS_D2   160
#define WS_W2T  192        // fp32 [144][32]
#define WS_W1BF 4800       // bf16 [256][1792]
#define WS_WHD  234176     // bf16 [256][256]  (mu rows 0..127, lv rows 128..255)
#define WS_HBUF 266944     // bf16 [32768][1792]
// total ws needed = (266944 + 29360128) * 4 B ~= 118.5 MB

typedef __attribute__((ext_vector_type(4))) float f32x4;
typedef __attribute__((ext_vector_type(8))) short short8;

static __device__ __forceinline__ ushort f2bf(float f) {
  __hip_bfloat16 h = __float2bfloat16(f);
  return *reinterpret_cast<ushort*>(&h);
}

// ---------------- K0: pack/convert weights into ws ----------------
__global__ __launch_bounds__(256) void k_pack(const float* __restrict__ w2,
    const float* __restrict__ fw, const float* __restrict__ muw,
    const float* __restrict__ lvw, float* __restrict__ ws) {
  int t = blockIdx.x * 256 + threadIdx.x;
  int stride = gridDim.x * 256;
  for (int d = t; d < 4608; d += stride) {       // conv2 w: [c2][c1][3][3] -> [(c1*9+k)][c2]
    int c2 = d / 144, rr = d % 144;
    ws[WS_W2T + rr * 32 + c2] = w2[d];
  }
  ushort* w1b = (ushort*)(ws + WS_W1BF);
  for (int d = t; d < 458752; d += stride) w1b[d] = f2bf(fw[d]);   // [n][k] bf16
  ushort* whd = (ushort*)(ws + WS_WHD);
  for (int d = t; d < 65536; d += stride) {
    int n2 = d >> 8, kk = d & 255;
    float v = (n2 < 128) ? muw[n2 * 256 + kk] : lvw[(n2 - 128) * 256 + kk];
    whd[d] = f2bf(v);
  }
}

// ---------------- K1: conv1 batch stats ----------------
__global__ __launch_bounds__(256) void k_stats1(const float* __restrict__ x,
    const float* __restrict__ w1, const float* __restrict__ b1, float* __restrict__ ws) {
  __shared__ float xbs[4][96];
  int tid = threadIdx.x, wv = tid >> 6, lane = tid & 63;
  int c = lane >> 2, nsub = lane & 3;
  float wr[9];
#pragma unroll
  for (int k = 0; k < 9; ++k) wr[k] = w1[c * 9 + k];
  float bias = b1[c];
  float s = 0.f, ss = 0.f;
  float* xsp = xbs[wv];
  for (int it = 0; it < 16; ++it) {
    int b = blockIdx.x * 64 + wv * 16 + it;
    for (int i = lane; i < 96; i += 64) xsp[i] = 0.f;
    __syncthreads();
    if (lane < 56) xsp[((lane >> 3) + 1) * 10 + (lane & 7) + 1] = x[(size_t)b * NPOS + lane];
    __syncthreads();
#pragma unroll
    for (int i = 0; i < 14; ++i) {
      int n = nsub * 14 + i;
      int base = (n >> 3) * 10 + (n & 7);
      float acc = bias;
#pragma unroll
      for (int ky = 0; ky < 3; ++ky)
#pragma unroll
        for (int kx = 0; kx < 3; ++kx)
          acc += wr[ky * 3 + kx] * xsp[base + ky * 10 + kx];
      s += acc; ss += acc * acc;
    }
    __syncthreads();
  }
  s += __shfl_xor(s, 1);  s += __shfl_xor(s, 2);
  ss += __shfl_xor(ss, 1); ss += __shfl_xor(ss, 2);
  if ((lane & 3) == 0) {
    atomicAdd(&ws[WS_SUM1 + c], s);
    atomicAdd(&ws[WS_SSQ1 + c], ss);
  }
}

// ---------------- K2/K4: finalize BN stats -> folded scale/shift ----------------
__global__ void k_finalize(const float* __restrict__ bnw, const float* __restrict__ bnb,
    const float* __restrict__ cb, float* __restrict__ ws,
    int nc, int so, int qo, int ao, int dof) {
  int c = threadIdx.x;
  if (c < nc) {
    float mean = ws[so + c] / CNT1;
    float var = ws[qo + c] / CNT1 - mean * mean;
    float a = bnw[c] * rsqrtf(var + 1e-5f);
    ws[ao + c] = a;
    ws[dof + c] = bnb[c] + a * (cb[c] - mean);   // conv bias folded in
  }
}

// ---------------- K3: conv2 batch stats (recompute conv1+bn1) ----------------
__global__ __launch_bounds__(256) void k_stats2(const float* __restrict__ x,
    const float* __restrict__ w1, const float* __restrict__ cb2, float* __restrict__ ws) {
  __shared__ float w2t_s[4608];
  __shared__ __align__(16) float h1ps[4][1440];
  __shared__ float xbs[4][96];
  int tid = threadIdx.x, wv = tid >> 6, lane = tid & 63;
  for (int i = tid; i < 4608; i += 256) w2t_s[i] = ws[WS_W2T + i];
  int c1l = lane >> 2, nsub = lane & 3;
  float wr[9];
#pragma unroll
  for (int k = 0; k < 9; ++k) wr[k] = w1[c1l * 9 + k];
  float a1 = ws[WS_A1 + c1l], d1 = ws[WS_D1 + c1l];
  int c2a = lane & 15, half = lane >> 4;
  float b2a = cb2[c2a], b2b = cb2[c2a + 16];
  int pos[14];
#pragma unroll
  for (int j = 0; j < 14; ++j) { int n = half * 14 + j; pos[j] = (n >> 3) * 10 + (n & 7); }
  float sA = 0.f, ssA = 0.f, sB = 0.f, ssB = 0.f;
  float* xsp = xbs[wv]; float* h1p = h1ps[wv];
  __syncthreads();
  for (int it = 0; it < 16; ++it) {
    int b = blockIdx.x * 64 + wv * 16 + it;
    for (int i = lane; i < 96; i += 64) xsp[i] = 0.f;
    for (int i = lane; i < 1440; i += 64) h1p[i] = 0.f;
    __syncthreads();
    if (lane < 56) xsp[((lane >> 3) + 1) * 10 + (lane & 7) + 1] = x[(size_t)b * NPOS + lane];
    __syncthreads();
#pragma unroll
    for (int i = 0; i < 14; ++i) {
      int n = nsub * 14 + i;
      int base = (n >> 3) * 10 + (n & 7);
      float acc = 0.f;
#pragma unroll
      for (int ky = 0; ky < 3; ++ky)
#pragma unroll
        for (int kx = 0; kx < 3; ++kx)
          acc += wr[ky * 3 + kx] * xsp[base + ky * 10 + kx];
      h1p[c1l * 90 + base + 11] = fmaxf(acc * a1 + d1, 0.f);
    }
    __syncthreads();
    float accA[14], accB[14];
#pragma unroll
    for (int j = 0; j < 14; ++j) { accA[j] = b2a; accB[j] = b2b; }
    for (int c1 = 0; c1 < 16; ++c1) {
      float wA[9], wB[9];
#pragma unroll
      for (int k = 0; k < 9; ++k) {
        wA[k] = w2t_s[(c1 * 9 + k) * 32 + c2a];
        wB[k] = w2t_s[(c1 * 9 + k) * 32 + c2a + 16];
      }
      const float* hp = &h1p[c1 * 90];
#pragma unroll
      for (int j = 0; j < 14; ++j) {
#pragma unroll
        for (int k9 = 0; k9 < 9; ++k9) {
          float hv = hp[pos[j] + (k9 / 3) * 10 + (k9 % 3)];
          accA[j] += wA[k9] * hv; accB[j] += wB[k9] * hv;
        }
      }
    }
#pragma unroll
    for (int j = 0; j < 14; ++j) {
      sA += accA[j]; ssA += accA[j] * accA[j];
      sB += accB[j]; ssB += accB[j] * accB[j];
    }
    __syncthreads();
  }
  sA += __shfl_xor(sA, 16); sA += __shfl_xor(sA, 32);
  ssA += __shfl_xor(ssA, 16); ssA += __shfl_xor(ssA, 32);
  sB += __shfl_xor(sB, 16); sB += __shfl_xor(sB, 32);
  ssB += __shfl_xor(ssB, 16); ssB += __shfl_xor(ssB, 32);
  if (lane < 16) {
    atomicAdd(&ws[WS_SUM2 + lane], sA);
    atomicAdd(&ws[WS_SSQ2 + lane], ssA);
    atomicAdd(&ws[WS_SUM2 + 16 + lane], sB);
    atomicAdd(&ws[WS_SSQ2 + 16 + lane], ssB);
  }
}

// ---------------- K5: conv1+conv2+attention -> h (bf16) to ws ----------------
__global__ __launch_bounds__(256) void k_conv_attn(
    const float* __restrict__ x, const float* __restrict__ w1,
    const float* __restrict__ qw, const float* __restrict__ qb_,
    const float* __restrict__ kw, const float* __restrict__ kb_,
    const float* __restrict__ vw, const float* __restrict__ vb_,
    const float* __restrict__ gp, const float* __restrict__ ws,
    ushort* __restrict__ hb) {
  __shared__ float w2t_s[4608];
  __shared__ __align__(16) float h1ps[4][1440];       // per-wave padded h1; later q/k
  __shared__ __align__(16) float h2Ts[4][2016];       // per-wave h2 transposed [56][36]
  __shared__ float xbs[4][96];
  int tid = threadIdx.x, wv = tid >> 6, lane = tid & 63;
  for (int i = tid; i < 4608; i += 256) w2t_s[i] = ws[WS_W2T + i];
  int c1l = lane >> 2, nsub = lane & 3;
  float wr[9];
#pragma unroll
  for (int k = 0; k < 9; ++k) wr[k] = w1[c1l * 9 + k];
  float a1 = ws[WS_A1 + c1l], d1 = ws[WS_D1 + c1l];
  int c2a = lane & 15, half = lane >> 4;
  float a2A = ws[WS_A2 + c2a], d2A = ws[WS_D2 + c2a];
  float a2B = ws[WS_A2 + c2a + 16], d2B = ws[WS_D2 + c2a + 16];
  int pos[14];
#pragma unroll
  for (int j = 0; j < 14; ++j) { int n = half * 14 + j; pos[j] = (n >> 3) * 10 + (n & 7); }
  float gamma = gp[0];
  float* h1p = h1ps[wv]; float* h2T = h2Ts[wv]; float* xsp = xbs[wv];
  for (int i = lane; i < 96; i += 64) xsp[i] = 0.f;
  __syncthreads();

  for (int r = 0; r < 8; ++r) {
    int b = blockIdx.x * 32 + wv * 8 + r;
    for (int i = lane; i < 1440; i += 64) h1p[i] = 0.f;
    if (lane < 56) xsp[((lane >> 3) + 1) * 10 + (lane & 7) + 1] = x[(size_t)b * NPOS + lane];
    __syncthreads();
    // conv1 + bn1 + relu
#pragma unroll
    for (int i = 0; i < 14; ++i) {
      int n = nsub * 14 + i;
      int base = (n >> 3) * 10 + (n & 7);
      float acc = 0.f;
#pragma unroll
      for (int ky = 0; ky < 3; ++ky)
#pragma unroll
        for (int kx = 0; kx < 3; ++kx)
          acc += wr[ky * 3 + kx] * xsp[base + ky * 10 + kx];
      h1p[c1l * 90 + base + 11] = fmaxf(acc * a1 + d1, 0.f);
    }
    __syncthreads();
    // conv2 + bn2 + relu -> h2T[n][c2]
    {
      float accA[14], accB[14];
#pragma unroll
      for (int j = 0; j < 14; ++j) { accA[j] = 0.f; accB[j] = 0.f; }
      for (int c1 = 0; c1 < 16; ++c1) {
        float wA[9], wB[9];
#pragma unroll
        for (int k = 0; k < 9; ++k) {
          wA[k] = w2t_s[(c1 * 9 + k) * 32 + c2a];
          wB[k] = w2t_s[(c1 * 9 + k) * 32 + c2a + 16];
        }
        const float* hp = &h1p[c1 * 90];
#pragma unroll
        for (int j = 0; j < 14; ++j) {
#pragma unroll
          for (int k9 = 0; k9 < 9; ++k9) {
            float hv = hp[pos[j] + (k9 / 3) * 10 + (k9 % 3)];
            accA[j] += wA[k9] * hv; accB[j] += wB[k9] * hv;
          }
        }
      }
#pragma unroll
      for (int j = 0; j < 14; ++j) {
        int n = half * 14 + j;
        h2T[n * 36 + c2a] = fmaxf(accA[j] * a2A + d2A, 0.f);
        h2T[n * 36 + c2a + 16] = fmaxf(accB[j] * a2B + d2B, 0.f);
      }
    }
    __syncthreads();
    // q,k projections -> h1p region: qT at [0,224), kT at [224,448)
    if (lane < 56) {
      float qa[4], ka[4];
#pragma unroll
      for (int o = 0; o < 4; ++o) { qa[o] = qb_[o]; ka[o] = kb_[o]; }
      const float4* hrow = (const float4*)&h2T[lane * 36];
#pragma unroll
      for (int g = 0; g < 8; ++g) {
        float4 hv = hrow[g];
#pragma unroll
        for (int o = 0; o < 4; ++o) {
          qa[o] += qw[o * 32 + g * 4 + 0] * hv.x + qw[o * 32 + g * 4 + 1] * hv.y
                 + qw[o * 32 + g * 4 + 2] * hv.z + qw[o * 32 + g * 4 + 3] * hv.w;
          ka[o] += kw[o * 32 + g * 4 + 0] * hv.x + kw[o * 32 + g * 4 + 1] * hv.y
                 + kw[o * 32 + g * 4 + 2] * hv.z + kw[o * 32 + g * 4 + 3] * hv.w;
        }
      }
      float4 qv = {qa[0], qa[1], qa[2], qa[3]};
      float4 kv = {ka[0], ka[1], ka[2], ka[3]};
      *(float4*)&h1p[lane * 4] = qv;
      *(float4*)&h1p[224 + lane * 4] = kv;
    }
    __syncthreads();
    // softmax(q^T k) fused with t = P @ h2  (v never materialized)
    float t[32];
    float inv = 0.f;
    if (lane < 56) {
      float4 q = *(const float4*)&h1p[lane * 4];
      float m = -1e30f;
      for (int j = 0; j < 56; ++j) {
        float4 kj = *(const float4*)&h1p[224 + j * 4];
        float s = q.x * kj.x + q.y * kj.y + q.z * kj.z + q.w * kj.w;
        m = fmaxf(m, s);
      }
#pragma unroll
      for (int cc = 0; cc < 32; ++cc) t[cc] = 0.f;
      float denom = 0.f;
      for (int j = 0; j < 56; ++j) {
        float4 kj = *(const float4*)&h1p[224 + j * 4];
        float s = q.x * kj.x + q.y * kj.y + q.z * kj.z + q.w * kj.w;
        float p = __expf(s - m);
        denom += p;
        const float4* h2r = (const float4*)&h2T[j * 36];
#pragma unroll
        for (int g = 0; g < 8; ++g) {
          float4 hv = h2r[g];
          t[g * 4 + 0] += p * hv.x; t[g * 4 + 1] += p * hv.y;
          t[g * 4 + 2] += p * hv.z; t[g * 4 + 3] += p * hv.w;
        }
      }
      inv = 1.f / denom;
    }
    // out = vb + inv*(vw @ t); residual; write bf16 h to global
    if (lane < 56) {
#pragma unroll
      for (int c = 0; c < 32; ++c) {
        float acc = 0.f;
#pragma unroll
        for (int cc = 0; cc < 32; ++cc) acc += vw[c * 32 + cc] * t[cc];
        float ov = vb_[c] + inv * acc;
        float hval = gamma * ov + h2T[lane * 36 + c];
        hb[(size_t)b * 1792 + c * 56 + lane] = f2bf(hval);
      }
    }
    __syncthreads();
  }
}

// ---------------- K6: fc1 + heads via bf16 MFMA ----------------
__global__ __launch_bounds__(256) void k_fc(
    const float* __restrict__ fc1b, const float* __restrict__ mub,
    const float* __restrict__ lvb, const float* __restrict__ ws,
    float* __restrict__ out) {
  __shared__ __align__(16) ushort At[64 * 64];     // swizzled [64][64] bf16
  __shared__ __align__(16) ushort Bt[256 * 64];    // swizzled [256][64] bf16
  __shared__ __align__(16) ushort Ft[64 * 256];    // swizzled [64][256] bf16
  const ushort* hbuf = (const ushort*)(ws + WS_HBUF);
  const ushort* w1bf = (const ushort*)(ws + WS_W1BF);
  const ushort* whd  = (const ushort*)(ws + WS_WHD);
  int tid = threadIdx.x, wv = tid >> 6, lane = tid & 63;
  int m0 = blockIdx.x * 64;
  int lr = lane & 15, lk = lane >> 4;

  f32x4 acc[4][4];
#pragma unroll
  for (int mi = 0; mi < 4; ++mi)
#pragma unroll
    for (int ni = 0; ni < 4; ++ni) { f32x4 z = {0.f, 0.f, 0.f, 0.f}; acc[mi][ni] = z; }

  int arow = tid >> 2, ac4 = tid & 3;
  for (int kk = 0; kk < 1792; kk += 64) {
    // stage A tile [64][64]: each thread 2x16B
#pragma unroll
    for (int i = 0; i < 2; ++i) {
      int ch = ac4 * 2 + i;
      uint4 av = *(const uint4*)&hbuf[(size_t)(m0 + arow) * 1792 + kk + ch * 8];
      *(uint4*)&At[arow * 64 + ((ch ^ (arow & 7)) * 8)] = av;
    }
    // stage B tile [256][64]: thread t stages row t
    {
      const ushort* src = &w1bf[tid * 1792 + kk];
#pragma unroll
      for (int i = 0; i < 8; ++i) {
        uint4 bv = *(const uint4*)&src[i * 8];
        *(uint4*)&Bt[tid * 64 + ((i ^ (tid & 7)) * 8)] = bv;
      }
    }
    __syncthreads();
#pragma unroll
    for (int t2 = 0; t2 < 2; ++t2) {
      short8 af[4], bfr[4];
#pragma unroll
      for (int mi = 0; mi < 4; ++mi) {
        int rr = mi * 16 + lr;
        int ch = (t2 * 4 + lk) ^ (rr & 7);
        af[mi] = *(const short8*)&At[rr * 64 + ch * 8];
      }
#pragma unroll
      for (int ni = 0; ni < 4; ++ni) {
        int rr = wv * 64 + ni * 16 + lr;
        int ch = (t2 * 4 + lk) ^ (rr & 7);
        bfr[ni] = *(const short8*)&Bt[rr * 64 + ch * 8];
      }
#pragma unroll
      for (int mi = 0; mi < 4; ++mi)
#pragma unroll
        for (int ni = 0; ni < 4; ++ni)
          acc[mi][ni] = __builtin_amdgcn_mfma_f32_16x16x32_bf16(af[mi], bfr[ni], acc[mi][ni], 0, 0, 0);
    }
    __syncthreads();
  }
  // epilogue 1: bias + relu -> Ft (swizzled [64][256] bf16)
#pragma unroll
  for (int ni = 0; ni < 4; ++ni) {
    int n = wv * 64 + ni * 16 + lr;
    float bj = fc1b[n];
    int lc = n >> 3;          // logical chunk 0..31
    int nl = n & 7;
#pragma unroll
    for (int mi = 0; mi < 4; ++mi) {
      f32x4 v = acc[mi][ni];
#pragma unroll
      for (int r = 0; r < 4; ++r) {
        int m = mi * 16 + lk * 4 + r;
        int chs = (lc & ~7) | ((lc & 7) ^ (m & 7));
        Ft[m * 256 + chs * 8 + nl] = f2bf(fmaxf(v[r] + bj, 0.f));
      }
    }
  }
  __syncthreads();
  // GEMM2: [64][256] @ [256][256]^T -> mu/lv
  f32x4 acc2[4][4];
#pragma unroll
  for (int mi = 0; mi < 4; ++mi)
#pragma unroll
    for (int ni = 0; ni < 4; ++ni) { f32x4 z = {0.f, 0.f, 0.f, 0.f}; acc2[mi][ni] = z; }
  for (int kk2 = 0; kk2 < 256; kk2 += 64) {
    const ushort* src = &whd[tid * 256 + kk2];
#pragma unroll
    for (int i = 0; i < 8; ++i) {
      uint4 bv = *(const uint4*)&src[i * 8];
      *(uint4*)&Bt[tid * 64 + ((i ^ (tid & 7)) * 8)] = bv;
    }
    __syncthreads();
#pragma unroll
    for (int t2 = 0; t2 < 2; ++t2) {
      short8 af[4], bfr[4];
#pragma unroll
      for (int mi = 0; mi < 4; ++mi) {
        int m = mi * 16 + lr;
        int lc = (kk2 >> 3) + t2 * 4 + lk;
        int chs = (lc & ~7) | ((lc & 7) ^ (m & 7));
        af[mi] = *(const short8*)&Ft[m * 256 + chs * 8];
      }
#pragma unroll
      for (int ni = 0; ni < 4; ++ni) {
        int rr = wv * 64 + ni * 16 + lr;
        int ch = (t2 * 4 + lk) ^ (rr & 7);
        bfr[ni] = *(const short8*)&Bt[rr * 64 + ch * 8];
      }
#pragma unroll
      for (int mi = 0; mi < 4; ++mi)
#pragma unroll
        for (int ni = 0; ni < 4; ++ni)
          acc2[mi][ni] = __builtin_amdgcn_mfma_f32_16x16x32_bf16(af[mi], bfr[ni], acc2[mi][ni], 0, 0, 0);
    }
    __syncthreads();
  }
  // epilogue 2: bias + write mu/lv
#pragma unroll
  for (int ni = 0; ni < 4; ++ni) {
    int n2 = wv * 64 + ni * 16 + lr;
    int isLv = (n2 >= 128);
    float bias2 = isLv ? lvb[n2 - 128] : mub[n2];
    size_t obase = isLv ? ((size_t)BTOT * 128 + (n2 - 128)) : (size_t)n2;
#pragma unroll
    for (int mi = 0; mi < 4; ++mi) {
      f32x4 v = acc2[mi][ni];
#pragma unroll
      for (int r = 0; r < 4; ++r) {
        int m = m0 + mi * 16 + lk * 4 + r;
        out[obase + (size_t)m * 128] = v[r] + bias2;
      }
    }
  }
}

extern "C" void kernel_launch(void* const* d_in, const int* in_sizes, int n_in,
                              void* d_out, int out_size, void* d_ws, size_t ws_size,
                              hipStream_t stream) {
  const float* x    = (const float*)d_in[0];
  const float* c1w  = (const float*)d_in[1];
  const float* c1b  = (const float*)d_in[2];
  const float* bn1w = (const float*)d_in[3];
  const float* bn1b = (const float*)d_in[4];
  const float* c2w  = (const float*)d_in[5];
  const float* c2b  = (const float*)d_in[6];
  const float* bn2w = (const float*)d_in[7];
  const float* bn2b = (const float*)d_in[8];
  const float* qw   = (const float*)d_in[9];
  const float* qb   = (const float*)d_in[10];
  const float* kw   = (const float*)d_in[11];
  const float* kb   = (const float*)d_in[12];
  const float* vw   = (const float*)d_in[13];
  const float* vb   = (const float*)d_in[14];
  const float* gm   = (const float*)d_in[15];
  const float* fw   = (const float*)d_in[16];
  const float* fb   = (const float*)d_in[17];
  const float* muw  = (const float*)d_in[18];
  const float* mub  = (const float*)d_in[19];
  const float* lvw  = (const float*)d_in[20];
  const float* lvb  = (const float*)d_in[21];
  float* ws = (float*)d_ws;
  float* out = (float*)d_out;
  ushort* hb = (ushort*)(ws + WS_HBUF);

  hipMemsetAsync(d_ws, 0, 96 * sizeof(float), stream);
  hipLaunchKernelGGL(k_pack, dim3(1024), dim3(256), 0, stream, c2w, fw, muw, lvw, ws);
  hipLaunchKernelGGL(k_stats1, dim3(512), dim3(256), 0, stream, x, c1w, c1b, ws);
  hipLaunchKernelGGL(k_finalize, dim3(1), dim3(64), 0, stream, bn1w, bn1b, c1b, ws,
                     16, WS_SUM1, WS_SSQ1, WS_A1, WS_D1);
  hipLaunchKernelGGL(k_stats2, dim3(512), dim3(256), 0, stream, x, c1w, c2b, ws);
  hipLaunchKernelGGL(k_finalize, dim3(1), dim3(64), 0, stream, bn2w, bn2b, c2b, ws,
                     32, WS_SUM2, WS_SSQ2, WS_A2, WS_D2);
  hipLaunchKernelGGL(k_conv_attn, dim3(1024), dim3(256), 0, stream, x, c1w,
                     qw, qb, kw, kb, vw, vb, gm, ws, hb);
  hipLaunchKernelGGL(k_fc, dim3(512), dim3(256), 0, stream, fb, mub, lvb, ws, out);
}

// Round 3
// 377.888 us; speedup vs baseline: 8.3682x; 3.4104x over previous
//
#include <hip/hip_runtime.h>
#include <hip/hip_bf16.h>

// Problem constants
#define BTOT 32768
#define NPOS 56            // 7*8
#define CNT1 1835008.0f    // BTOT*NPOS

// ws float offsets
#define WS_SUM1 0
#define WS_SSQ1 16
#define WS_SUM2 32
#define WS_SSQ2 64
#define WS_A1   96
#define WS_D1   112
#define WS_A2   128
#define WS_D2   160
#define WS_W2R  192        // f16 [32 c2][160]  (k = shift*16 + c1, shift 9 = zeros)
#define WS_VWH  2752       // f16 [32 c][32 cc]
#define WS_W1BF 3264       // f16 [256 n][1792 k'] with k' = pos*32 + c2
#define WS_WHD  232640     // f16 [256][256] (mu rows 0..127, lv rows 128..255)
#define WS_Y2H  265408     // f16 [32768][1792]: y2 pre-BN, later overwritten by h
// total = 29625536 floats ~= 118.5 MB

typedef __attribute__((ext_vector_type(4))) float f32x4;
typedef __attribute__((ext_vector_type(8))) _Float16 f16x8;

static __device__ __forceinline__ ushort f2h(float f) {
  _Float16 h = (_Float16)f; return __builtin_bit_cast(ushort, h);
}
static __device__ __forceinline__ float h2f(ushort u) {
  _Float16 h = __builtin_bit_cast(_Float16, u); return (float)h;
}

// ---------------- K0: pack/convert weights into ws ----------------
__global__ __launch_bounds__(256) void k_pack(const float* __restrict__ w2,
    const float* __restrict__ vw, const float* __restrict__ fw,
    const float* __restrict__ muw, const float* __restrict__ lvw,
    float* __restrict__ ws) {
  int t = blockIdx.x * 256 + threadIdx.x;
  int stride = gridDim.x * 256;
  ushort* w2r = (ushort*)(ws + WS_W2R);
  for (int d = t; d < 5120; d += stride) {
    int c2 = d / 160, rem = d % 160, s = rem >> 4, c1 = rem & 15;
    w2r[d] = f2h(s < 9 ? w2[c2 * 144 + c1 * 9 + s] : 0.f);
  }
  ushort* vwh = (ushort*)(ws + WS_VWH);
  for (int d = t; d < 1024; d += stride) vwh[d] = f2h(vw[d]);
  ushort* w1b = (ushort*)(ws + WS_W1BF);
  for (int d = t; d < 458752; d += stride) {
    int n = d / 1792, kk = d % 1792, pos = kk >> 5, c2 = kk & 31;
    w1b[d] = f2h(fw[n * 1792 + c2 * 56 + pos]);
  }
  ushort* whd = (ushort*)(ws + WS_WHD);
  for (int d = t; d < 65536; d += stride) {
    int n2 = d >> 8, kk = d & 255;
    whd[d] = f2h(n2 < 128 ? muw[n2 * 256 + kk] : lvw[(n2 - 128) * 256 + kk]);
  }
}

// ---------------- K1: conv1 batch stats (biasless: BN cancels conv bias) ----------------
__global__ __launch_bounds__(256) void k_stats1(const float* __restrict__ x,
    const float* __restrict__ w1, float* __restrict__ ws) {
  __shared__ float xbs[4][96];
  int tid = threadIdx.x, wv = tid >> 6, lane = tid & 63;
  int c = lane >> 2, nsub = lane & 3;
  float wr[9];
#pragma unroll
  for (int k = 0; k < 9; ++k) wr[k] = w1[c * 9 + k];
  float s = 0.f, ss = 0.f;
  float* xsp = xbs[wv];
  for (int i = lane; i < 96; i += 64) xsp[i] = 0.f;
  for (int it = 0; it < 16; ++it) {
    int b = blockIdx.x * 64 + wv * 16 + it;
    __syncthreads();
    if (lane < 56) xsp[((lane >> 3) + 1) * 10 + (lane & 7) + 1] = x[(size_t)b * NPOS + lane];
    __syncthreads();
#pragma unroll
    for (int i = 0; i < 14; ++i) {
      int n = nsub * 14 + i;
      int base = (n >> 3) * 10 + (n & 7);
      float acc = 0.f;
#pragma unroll
      for (int ky = 0; ky < 3; ++ky)
#pragma unroll
        for (int kx = 0; kx < 3; ++kx)
          acc += wr[ky * 3 + kx] * xsp[base + ky * 10 + kx];
      s += acc; ss += acc * acc;
    }
  }
  s += __shfl_xor(s, 1);  s += __shfl_xor(s, 2);
  ss += __shfl_xor(ss, 1); ss += __shfl_xor(ss, 2);
  if ((lane & 3) == 0) {
    atomicAdd(&ws[WS_SUM1 + c], s);
    atomicAdd(&ws[WS_SSQ1 + c], ss);
  }
}

// ---------------- finalize BN stats -> scale/shift ----------------
__global__ void k_finalize(const float* __restrict__ bnw, const float* __restrict__ bnb,
    float* __restrict__ ws, int nc, int so, int qo, int ao, int dof) {
  int c = threadIdx.x;
  if (c < nc) {
    float mean = ws[so + c] / CNT1;
    float var = ws[qo + c] / CNT1 - mean * mean;
    float a = bnw[c] * rsqrtf(var + 1e-5f);
    ws[ao + c] = a;
    ws[dof + c] = bnb[c] - a * mean;
  }
}

// ---------------- K2: conv1 + conv2(MFMA) -> y2 (f16) + bn2 stats ----------------
__global__ __launch_bounds__(256) void k_conv(const float* __restrict__ x,
    const float* __restrict__ w1, float* __restrict__ ws) {
  __shared__ ushort h1T[4][112 * 32];   // per-wave [112 padded-pos][32 halves (c1 in 0..15)]
  __shared__ ushort y2l[4][64 * 32];    // per-wave [64 pos][32 c2] f16
  __shared__ float xs4[4][96];
  __shared__ float sb[32], ssb[32];
  const ushort* w2r = (const ushort*)(ws + WS_W2R);
  ushort* y2h = (ushort*)(ws + WS_Y2H);
  int tid = threadIdx.x, wv = tid >> 6, lane = tid & 63;
  int lr = lane & 15, lk = lane >> 4;
  if (tid < 32) { sb[tid] = 0.f; ssb[tid] = 0.f; }
  ushort* h1 = h1T[wv];
  ushort* yl = y2l[wv];
  float* xsp = xs4[wv];
  for (int i = lane; i < 1792; i += 64) ((uint*)h1)[i] = 0;
  for (int i = lane; i < 96; i += 64) xsp[i] = 0.f;
  // A-fragments of conv2 weights (constant per kernel)
  f16x8 afr[2][5];
#pragma unroll
  for (int mi = 0; mi < 2; ++mi)
#pragma unroll
    for (int s2 = 0; s2 < 5; ++s2)
      afr[mi][s2] = *(const f16x8*)(w2r + (mi * 16 + lr) * 160 + s2 * 32 + lk * 8);
  // conv1 setup
  int c1l = lane >> 2, nsub = lane & 3;
  float wr[9];
#pragma unroll
  for (int k = 0; k < 9; ++k) wr[k] = w1[c1l * 9 + k];
  float a1 = ws[WS_A1 + c1l], d1 = ws[WS_D1 + c1l];
  // B-frag geometry
  int hi = lk >> 1, lo = lk & 1;
  int base4[4];
#pragma unroll
  for (int ni = 0; ni < 4; ++ni) {
    int n = lr + 16 * ni;
    base4[ni] = (n < 56) ? (n >> 3) * 10 + (n & 7) : 88;  // >=56 -> all-zero rows
  }
  const int dA_[5] = {0, 2, 11, 20, 22};
  const int dB_[5] = {1, 10, 12, 21, 0};
  float s8[8], ss8[8];
#pragma unroll
  for (int i = 0; i < 8; ++i) { s8[i] = 0.f; ss8[i] = 0.f; }
  __syncthreads();

  for (int r8 = 0; r8 < 8; ++r8) {
    int b = blockIdx.x * 32 + wv * 8 + r8;
    if (lane < 56) xsp[((lane >> 3) + 1) * 10 + (lane & 7) + 1] = x[(size_t)b * NPOS + lane];
    // conv1 + bn1 + relu -> h1T (wave-private, LDS ops in-order within wave)
#pragma unroll
    for (int i = 0; i < 14; ++i) {
      int n = nsub * 14 + i;
      int base = (n >> 3) * 10 + (n & 7);
      float acc = 0.f;
#pragma unroll
      for (int ky = 0; ky < 3; ++ky)
#pragma unroll
        for (int kx = 0; kx < 3; ++kx)
          acc += wr[ky * 3 + kx] * xsp[base + ky * 10 + kx];
      h1[(base + 11) * 32 + c1l] = f2h(fmaxf(acc * a1 + d1, 0.f));
    }
    // conv2 via MFMA: y2[c2][pos] = sum_k w2r[c2][k] * h1shift[k][pos]
    f32x4 acc2[2][4];
#pragma unroll
    for (int mi = 0; mi < 2; ++mi)
#pragma unroll
      for (int ni = 0; ni < 4; ++ni) { f32x4 z = {0.f, 0.f, 0.f, 0.f}; acc2[mi][ni] = z; }
#pragma unroll
    for (int s2 = 0; s2 < 5; ++s2) {
      f16x8 bf[4];
#pragma unroll
      for (int ni = 0; ni < 4; ++ni) {
        int row;
        if (s2 == 4) row = hi ? 104 : (base4[ni] + 22);
        else row = base4[ni] + (hi ? dB_[s2] : dA_[s2]);
        bf[ni] = *(const f16x8*)(h1 + row * 32 + lo * 8);
      }
#pragma unroll
      for (int mi = 0; mi < 2; ++mi)
#pragma unroll
        for (int ni = 0; ni < 4; ++ni)
          acc2[mi][ni] = __builtin_amdgcn_mfma_f32_16x16x32_f16(afr[mi][s2], bf[ni], acc2[mi][ni], 0, 0, 0);
    }
    // stats + pack to y2l [pos][c2]
#pragma unroll
    for (int mi = 0; mi < 2; ++mi)
#pragma unroll
      for (int ni = 0; ni < 4; ++ni) {
        f32x4 v = acc2[mi][ni];
        int pos = lr + 16 * ni;
        s8[mi * 4 + 0] += v[0]; ss8[mi * 4 + 0] += v[0] * v[0];
        s8[mi * 4 + 1] += v[1]; ss8[mi * 4 + 1] += v[1] * v[1];
        s8[mi * 4 + 2] += v[2]; ss8[mi * 4 + 2] += v[2] * v[2];
        s8[mi * 4 + 3] += v[3]; ss8[mi * 4 + 3] += v[3] * v[3];
        uint p01 = (uint)f2h(v[0]) | ((uint)f2h(v[1]) << 16);
        uint p23 = (uint)f2h(v[2]) | ((uint)f2h(v[3]) << 16);
        ((uint*)yl)[pos * 16 + lk * 2 + 8 * mi] = p01;
        ((uint*)yl)[pos * 16 + lk * 2 + 8 * mi + 1] = p23;
      }
    // copy first 56 rows -> global
    uint4* dst = (uint4*)y2h + (size_t)b * 224;
    for (int i = lane; i < 224; i += 64) dst[i] = ((const uint4*)yl)[i];
  }
  // reduce stats over the 16 pos-col lanes
#pragma unroll
  for (int i = 0; i < 8; ++i) {
    s8[i] += __shfl_xor(s8[i], 1);  s8[i] += __shfl_xor(s8[i], 2);
    s8[i] += __shfl_xor(s8[i], 4);  s8[i] += __shfl_xor(s8[i], 8);
    ss8[i] += __shfl_xor(ss8[i], 1); ss8[i] += __shfl_xor(ss8[i], 2);
    ss8[i] += __shfl_xor(ss8[i], 4); ss8[i] += __shfl_xor(ss8[i], 8);
  }
  if (lr == 0) {
#pragma unroll
    for (int i = 0; i < 8; ++i) {
      int c2 = lk * 4 + (i & 3) + 16 * (i >> 2);
      atomicAdd(&sb[c2], s8[i]);
      atomicAdd(&ssb[c2], ss8[i]);
    }
  }
  __syncthreads();
  if (tid < 32) {
    atomicAdd(&ws[WS_SUM2 + tid], sb[tid]);
    atomicAdd(&ws[WS_SSQ2 + tid], ssb[tid]);
  }
}

// ---------------- K3: attention (scores VALU, PV via MFMA), h overwrites y2 ----------------
__global__ __launch_bounds__(256) void k_attn(
    const float* __restrict__ qw, const float* __restrict__ qb_,
    const float* __restrict__ kw, const float* __restrict__ kb_,
    const float* __restrict__ vb_, const float* __restrict__ gp,
    float* __restrict__ ws) {
  __shared__ ushort h2m[4][64 * 32];   // [pos][c2] f16, XOR-swizzled (row&3)<<4
  __shared__ ushort Pm[4][64 * 64];    // [i][j] f16, XOR (row&7)<<4
  __shared__ ushort gm[4][32 * 64];    // [c][j] f16, XOR (row&7)<<4
  __shared__ float klds[4][64 * 4];
  __shared__ float invl[4][64];
  const ushort* vwh = (const ushort*)(ws + WS_VWH);
  ushort* y2h = (ushort*)(ws + WS_Y2H);
  int tid = threadIdx.x, wv = tid >> 6, lane = tid & 63;
  int lr = lane & 15, lk = lane >> 4;
  ushort* h2 = h2m[wv]; ushort* P = Pm[wv]; ushort* gl = gm[wv];
  float* kl = klds[wv]; float* iv = invl[wv];
  for (int i = lane; i < 2048; i += 64) ((uint*)P)[i] = 0;
  for (int i = lane; i < 1024; i += 64) ((uint*)h2)[i] = 0;
  iv[lane] = 0.f;
  float gamma = gp[0];
  f16x8 vwf[2];
  float vbv[2];
#pragma unroll
  for (int ni = 0; ni < 2; ++ni) {
    vwf[ni] = *(const f16x8*)(vwh + (lr + 16 * ni) * 32 + lk * 8);
    vbv[ni] = vb_[lr + 16 * ni];
  }
  float qb0 = qb_[0], qb1 = qb_[1], qb2 = qb_[2], qb3 = qb_[3];
  float kb0 = kb_[0], kb1 = kb_[1], kb2 = kb_[2], kb3 = kb_[3];

  for (int r8 = 0; r8 < 8; ++r8) {
    int b = blockIdx.x * 32 + wv * 8 + r8;
    float qa0, qa1, qa2, qa3;
    if (lane < 56) {
      const uint4* src = (const uint4*)y2h + (size_t)b * 224 + lane * 4;
      uint4 rows[4];
#pragma unroll
      for (int g = 0; g < 4; ++g) rows[g] = src[g];
      float h2row[32];
#pragma unroll
      for (int g = 0; g < 4; ++g)
#pragma unroll
        for (int hh = 0; hh < 8; ++hh) {
          int cc = g * 8 + hh;
          float yv = h2f(((const ushort*)&rows[g])[hh]);
          h2row[cc] = fmaxf(ws[WS_A2 + cc] * yv + ws[WS_D2 + cc], 0.f);
        }
      // h2 -> LDS (swizzled)
#pragma unroll
      for (int pr = 0; pr < 16; ++pr) {
        uint pk = (uint)f2h(h2row[2 * pr]) | ((uint)f2h(h2row[2 * pr + 1]) << 16);
        *(uint*)((char*)h2 + ((lane * 64 + pr * 4) ^ ((lane & 3) << 4))) = pk;
      }
      // q,k projections
      qa0 = qb0; qa1 = qb1; qa2 = qb2; qa3 = qb3;
      float ka0 = kb0, ka1 = kb1, ka2 = kb2, ka3 = kb3;
#pragma unroll
      for (int cc = 0; cc < 32; ++cc) {
        float hv = h2row[cc];
        qa0 += qw[cc] * hv;      qa1 += qw[32 + cc] * hv;
        qa2 += qw[64 + cc] * hv; qa3 += qw[96 + cc] * hv;
        ka0 += kw[cc] * hv;      ka1 += kw[32 + cc] * hv;
        ka2 += kw[64 + cc] * hv; ka3 += kw[96 + cc] * hv;
      }
      float4 kv = {ka0, ka1, ka2, ka3};
      *(float4*)&kl[lane * 4] = kv;
    }
    if (lane < 56) {
      float m = -1e30f;
#pragma unroll 8
      for (int j = 0; j < 56; ++j) {
        float4 kj = *(const float4*)&kl[j * 4];
        float s = qa0 * kj.x + qa1 * kj.y + qa2 * kj.z + qa3 * kj.w;
        m = fmaxf(m, s);
      }
      float denom = 0.f;
#pragma unroll 4
      for (int jp = 0; jp < 28; ++jp) {
        float4 k0 = *(const float4*)&kl[jp * 8];
        float4 k1 = *(const float4*)&kl[jp * 8 + 4];
        float s0 = qa0 * k0.x + qa1 * k0.y + qa2 * k0.z + qa3 * k0.w;
        float s1 = qa0 * k1.x + qa1 * k1.y + qa2 * k1.z + qa3 * k1.w;
        float e0 = __expf(s0 - m), e1 = __expf(s1 - m);
        denom += e0 + e1;
        uint pk = (uint)f2h(e0) | ((uint)f2h(e1) << 16);
        *(uint*)((char*)P + ((lane * 128 + jp * 4) ^ ((lane & 7) << 4))) = pk;
      }
#pragma unroll
      for (int jp = 28; jp < 32; ++jp)
        *(uint*)((char*)P + ((lane * 128 + jp * 4) ^ ((lane & 7) << 4))) = 0;
      iv[lane] = 1.f / denom;
    }
    // gT = h2 @ vw^T  : [64 j][32 c]
    f32x4 ga[4][2];
#pragma unroll
    for (int mi = 0; mi < 4; ++mi)
#pragma unroll
      for (int ni = 0; ni < 2; ++ni) { f32x4 z = {0.f, 0.f, 0.f, 0.f}; ga[mi][ni] = z; }
#pragma unroll
    for (int mi = 0; mi < 4; ++mi) {
      int rw = lr + 16 * mi;
      f16x8 af = *(const f16x8*)((const char*)h2 + ((rw * 64 + lk * 16) ^ ((rw & 3) << 4)));
#pragma unroll
      for (int ni = 0; ni < 2; ++ni)
        ga[mi][ni] = __builtin_amdgcn_mfma_f32_16x16x32_f16(af, vwf[ni], ga[mi][ni], 0, 0, 0);
    }
    // scatter gT -> gl [c][j] f16 (swizzled)
#pragma unroll
    for (int mi = 0; mi < 4; ++mi)
#pragma unroll
      for (int ni = 0; ni < 2; ++ni) {
        f32x4 v = ga[mi][ni];
        int c = lr + 16 * ni;
        int jb2 = (lk * 4 + 16 * mi) * 2;   // byte offset of j base
        uint p01 = (uint)f2h(v[0]) | ((uint)f2h(v[1]) << 16);
        uint p23 = (uint)f2h(v[2]) | ((uint)f2h(v[3]) << 16);
        *(uint*)((char*)gl + ((c * 128 + jb2) ^ ((c & 7) << 4))) = p01;
        *(uint*)((char*)gl + ((c * 128 + jb2 + 4) ^ ((c & 7) << 4))) = p23;
      }
    // out = P @ gT : [64 i][32 c]
    f32x4 oa[4][2];
#pragma unroll
    for (int mi = 0; mi < 4; ++mi)
#pragma unroll
      for (int ni = 0; ni < 2; ++ni) { f32x4 z = {0.f, 0.f, 0.f, 0.f}; oa[mi][ni] = z; }
#pragma unroll
    for (int ks = 0; ks < 2; ++ks) {
      f16x8 bfv[2];
#pragma unroll
      for (int ni = 0; ni < 2; ++ni) {
        int c = lr + 16 * ni;
        bfv[ni] = *(const f16x8*)((const char*)gl + ((c * 128 + ks * 64 + lk * 16) ^ ((c & 7) << 4)));
      }
#pragma unroll
      for (int mi = 0; mi < 4; ++mi) {
        int rw = lr + 16 * mi;
        f16x8 pf = *(const f16x8*)((const char*)P + ((rw * 128 + ks * 64 + lk * 16) ^ ((rw & 7) << 4)));
#pragma unroll
        for (int ni = 0; ni < 2; ++ni)
          oa[mi][ni] = __builtin_amdgcn_mfma_f32_16x16x32_f16(pf, bfv[ni], oa[mi][ni], 0, 0, 0);
      }
    }
    // epilogue: h = gamma*(vb + inv*out) + h2, in-place into h2 LDS
#pragma unroll
    for (int mi = 0; mi < 4; ++mi) {
      float4 inv4 = *(const float4*)&iv[mi * 16 + lk * 4];
      float invr[4] = {inv4.x, inv4.y, inv4.z, inv4.w};
#pragma unroll
      for (int ni = 0; ni < 2; ++ni) {
        f32x4 v = oa[mi][ni];
        int c = lr + 16 * ni;
#pragma unroll
        for (int r = 0; r < 4; ++r) {
          int i = mi * 16 + lk * 4 + r;
          if (i < 56) {
            char* hp = (char*)h2 + ((i * 64 + c * 2) ^ ((i & 3) << 4));
            float h2v = h2f(*(ushort*)hp);
            *(ushort*)hp = f2h(gamma * (vbv[ni] + invr[r] * v[r]) + h2v);
          }
        }
      }
    }
    // copy h rows 0..55 -> global (unswizzle)
    uint4* dst = (uint4*)y2h + (size_t)b * 224;
    for (int i2 = lane; i2 < 224; i2 += 64) {
      int row = i2 >> 2, slot = i2 & 3;
      dst[i2] = *(const uint4*)((const char*)h2 + row * 64 + ((slot ^ (row & 3)) * 16));
    }
  }
}

// ---------------- K4: fc1 + heads via f16 MFMA ----------------
__global__ __launch_bounds__(256) void k_fc(
    const float* __restrict__ fc1b, const float* __restrict__ mub,
    const float* __restrict__ lvb, const float* __restrict__ ws,
    float* __restrict__ out) {
  __shared__ __align__(16) ushort At[64 * 64];
  __shared__ __align__(16) ushort Bt[256 * 64];
  __shared__ __align__(16) ushort Ft[64 * 256];
  const ushort* hbuf = (const ushort*)(ws + WS_Y2H);
  const ushort* w1bf = (const ushort*)(ws + WS_W1BF);
  const ushort* whd  = (const ushort*)(ws + WS_WHD);
  int tid = threadIdx.x, wv = tid >> 6, lane = tid & 63;
  int m0 = blockIdx.x * 64;
  int lr = lane & 15, lk = lane >> 4;

  f32x4 acc[4][4];
#pragma unroll
  for (int mi = 0; mi < 4; ++mi)
#pragma unroll
    for (int ni = 0; ni < 4; ++ni) { f32x4 z = {0.f, 0.f, 0.f, 0.f}; acc[mi][ni] = z; }

  int arow = tid >> 2, ac4 = tid & 3;
  for (int kk = 0; kk < 1792; kk += 64) {
#pragma unroll
    for (int i = 0; i < 2; ++i) {
      int ch = ac4 * 2 + i;
      uint4 av = *(const uint4*)&hbuf[(size_t)(m0 + arow) * 1792 + kk + ch * 8];
      *(uint4*)&At[arow * 64 + ((ch ^ (arow & 7)) * 8)] = av;
    }
    {
      const ushort* src = &w1bf[tid * 1792 + kk];
#pragma unroll
      for (int i = 0; i < 8; ++i) {
        uint4 bv = *(const uint4*)&src[i * 8];
        *(uint4*)&Bt[tid * 64 + ((i ^ (tid & 7)) * 8)] = bv;
      }
    }
    __syncthreads();
#pragma unroll
    for (int t2 = 0; t2 < 2; ++t2) {
      f16x8 af[4], bfr[4];
#pragma unroll
      for (int mi = 0; mi < 4; ++mi) {
        int rr = mi * 16 + lr;
        int ch = (t2 * 4 + lk) ^ (rr & 7);
        af[mi] = *(const f16x8*)&At[rr * 64 + ch * 8];
      }
#pragma unroll
      for (int ni = 0; ni < 4; ++ni) {
        int rr = wv * 64 + ni * 16 + lr;
        int ch = (t2 * 4 + lk) ^ (rr & 7);
        bfr[ni] = *(const f16x8*)&Bt[rr * 64 + ch * 8];
      }
#pragma unroll
      for (int mi = 0; mi < 4; ++mi)
#pragma unroll
        for (int ni = 0; ni < 4; ++ni)
          acc[mi][ni] = __builtin_amdgcn_mfma_f32_16x16x32_f16(af[mi], bfr[ni], acc[mi][ni], 0, 0, 0);
    }
    __syncthreads();
  }
#pragma unroll
  for (int ni = 0; ni < 4; ++ni) {
    int n = wv * 64 + ni * 16 + lr;
    float bj = fc1b[n];
    int lc = n >> 3;
    int nl = n & 7;
#pragma unroll
    for (int mi = 0; mi < 4; ++mi) {
      f32x4 v = acc[mi][ni];
#pragma unroll
      for (int r = 0; r < 4; ++r) {
        int m = mi * 16 + lk * 4 + r;
        int chs = (lc & ~7) | ((lc & 7) ^ (m & 7));
        Ft[m * 256 + chs * 8 + nl] = f2h(fmaxf(v[r] + bj, 0.f));
      }
    }
  }
  __syncthreads();
  f32x4 acc2[4][4];
#pragma unroll
  for (int mi = 0; mi < 4; ++mi)
#pragma unroll
    for (int ni = 0; ni < 4; ++ni) { f32x4 z = {0.f, 0.f, 0.f, 0.f}; acc2[mi][ni] = z; }
  for (int kk2 = 0; kk2 < 256; kk2 += 64) {
    const ushort* src = &whd[tid * 256 + kk2];
#pragma unroll
    for (int i = 0; i < 8; ++i) {
      uint4 bv = *(const uint4*)&src[i * 8];
      *(uint4*)&Bt[tid * 64 + ((i ^ (tid & 7)) * 8)] = bv;
    }
    __syncthreads();
#pragma unroll
    for (int t2 = 0; t2 < 2; ++t2) {
      f16x8 af[4], bfr[4];
#pragma unroll
      for (int mi = 0; mi < 4; ++mi) {
        int m = mi * 16 + lr;
        int lc = (kk2 >> 3) + t2 * 4 + lk;
        int chs = (lc & ~7) | ((lc & 7) ^ (m & 7));
        af[mi] = *(const f16x8*)&Ft[m * 256 + chs * 8];
      }
#pragma unroll
      for (int ni = 0; ni < 4; ++ni) {
        int rr = wv * 64 + ni * 16 + lr;
        int ch = (t2 * 4 + lk) ^ (rr & 7);
        bfr[ni] = *(const f16x8*)&Bt[rr * 64 + ch * 8];
      }
#pragma unroll
      for (int mi = 0; mi < 4; ++mi)
#pragma unroll
        for (int ni = 0; ni < 4; ++ni)
          acc2[mi][ni] = __builtin_amdgcn_mfma_f32_16x16x32_f16(af[mi], bfr[ni], acc2[mi][ni], 0, 0, 0);
    }
    __syncthreads();
  }
#pragma unroll
  for (int ni = 0; ni < 4; ++ni) {
    int n2 = wv * 64 + ni * 16 + lr;
    int isLv = (n2 >= 128);
    float bias2 = isLv ? lvb[n2 - 128] : mub[n2];
    size_t obase = isLv ? ((size_t)BTOT * 128 + (n2 - 128)) : (size_t)n2;
#pragma unroll
    for (int mi = 0; mi < 4; ++mi) {
      f32x4 v = acc2[mi][ni];
#pragma unroll
      for (int r = 0; r < 4; ++r) {
        int m = m0 + mi * 16 + lk * 4 + r;
        out[obase + (size_t)m * 128] = v[r] + bias2;
      }
    }
  }
}

extern "C" void kernel_launch(void* const* d_in, const int* in_sizes, int n_in,
                              void* d_out, int out_size, void* d_ws, size_t ws_size,
                              hipStream_t stream) {
  const float* x    = (const float*)d_in[0];
  const float* c1w  = (const float*)d_in[1];
  const float* bn1w = (const float*)d_in[3];
  const float* bn1b = (const float*)d_in[4];
  const float* c2w  = (const float*)d_in[5];
  const float* bn2w = (const float*)d_in[7];
  const float* bn2b = (const float*)d_in[8];
  const float* qw   = (const float*)d_in[9];
  const float* qb   = (const float*)d_in[10];
  const float* kw   = (const float*)d_in[11];
  const float* kb   = (const float*)d_in[12];
  const float* vw   = (const float*)d_in[13];
  const float* vb   = (const float*)d_in[14];
  const float* gm   = (const float*)d_in[15];
  const float* fw   = (const float*)d_in[16];
  const float* fb   = (const float*)d_in[17];
  const float* muw  = (const float*)d_in[18];
  const float* mub  = (const float*)d_in[19];
  const float* lvw  = (const float*)d_in[20];
  const float* lvb  = (const float*)d_in[21];
  float* ws = (float*)d_ws;
  float* out = (float*)d_out;

  hipMemsetAsync(d_ws, 0, 96 * sizeof(float), stream);
  hipLaunchKernelGGL(k_pack, dim3(1024), dim3(256), 0, stream, c2w, vw, fw, muw, lvw, ws);
  hipLaunchKernelGGL(k_stats1, dim3(512), dim3(256), 0, stream, x, c1w, ws);
  hipLaunchKernelGGL(k_finalize, dim3(1), dim3(64), 0, stream, bn1w, bn1b, ws,
                     16, WS_SUM1, WS_SSQ1, WS_A1, WS_D1);
  hipLaunchKernelGGL(k_conv, dim3(1024), dim3(256), 0, stream, x, c1w, ws);
  hipLaunchKernelGGL(k_finalize, dim3(1), dim3(64), 0, stream, bn2w, bn2b, ws,
                     32, WS_SUM2, WS_SSQ2, WS_A2, WS_D2);
  hipLaunchKernelGGL(k_attn, dim3(1024), dim3(256), 0, stream,
                     qw, qb, kw, kb, vb, gm, ws);
  hipLaunchKernelGGL(k_fc, dim3(512), dim3(256), 0, stream, fb, mub, lvb, ws, out);
}

// Round 5
// 294.768 us; speedup vs baseline: 10.7279x; 1.2820x over previous
//
#include <hip/hip_runtime.h>
#include <hip/hip_bf16.h>

// Problem constants
#define BTOT 32768
#define NPOS 56            // 7*8
#define CNT1 1835008.0f    // BTOT*NPOS
#define LOG2E 1.4426950408889634f

// ws float offsets
#define WS_SUM1 0
#define WS_SSQ1 16
#define WS_SUM2 32
#define WS_SSQ2 64
#define WS_A1   96
#define WS_D1   112
#define WS_A2   128
#define WS_D2   160
#define WS_W2R  192        // f16 [32 c2][160]  (k = shift*16 + c1, shift 9 = zeros)
#define WS_VWH  2752       // f16 [32 c][32 cc]
#define WS_W1BF 3264       // f16 [256 n][1792 k'] with k' = pos*32 + c2
#define WS_WHD  232640     // f16 [256][256] (mu rows 0..127, lv rows 128..255)
#define WS_Y2H  265408     // f16 [32768][1792]: y2 pre-BN, later overwritten by h
// total = 29625536 floats ~= 118.5 MB

typedef __attribute__((ext_vector_type(4))) float f32x4;
typedef __attribute__((ext_vector_type(8))) _Float16 f16x8;

static __device__ __forceinline__ ushort f2h(float f) {
  _Float16 h = (_Float16)f; return __builtin_bit_cast(ushort, h);
}
static __device__ __forceinline__ float h2f(ushort u) {
  _Float16 h = __builtin_bit_cast(_Float16, u); return (float)h;
}
static __device__ __forceinline__ uint pk2(float a, float b) {
  auto t = __builtin_amdgcn_cvt_pkrtz(a, b);
  return __builtin_bit_cast(uint, t);
}

// ---------------- K0: pack/convert weights into ws ----------------
__global__ __launch_bounds__(256) void k_pack(const float* __restrict__ w2,
    const float* __restrict__ vw, const float* __restrict__ fw,
    const float* __restrict__ muw, const float* __restrict__ lvw,
    float* __restrict__ ws) {
  int t = blockIdx.x * 256 + threadIdx.x;
  int stride = gridDim.x * 256;
  ushort* w2r = (ushort*)(ws + WS_W2R);
  for (int d = t; d < 5120; d += stride) {
    int c2 = d / 160, rem = d % 160, s = rem >> 4, c1 = rem & 15;
    w2r[d] = f2h(s < 9 ? w2[c2 * 144 + c1 * 9 + s] : 0.f);
  }
  ushort* vwh = (ushort*)(ws + WS_VWH);
  for (int d = t; d < 1024; d += stride) vwh[d] = f2h(vw[d]);
  ushort* w1b = (ushort*)(ws + WS_W1BF);
  for (int d = t; d < 458752; d += stride) {
    int n = d / 1792, kk = d % 1792, pos = kk >> 5, c2 = kk & 31;
    w1b[d] = f2h(fw[n * 1792 + c2 * 56 + pos]);
  }
  ushort* whd = (ushort*)(ws + WS_WHD);
  for (int d = t; d < 65536; d += stride) {
    int n2 = d >> 8, kk = d & 255;
    whd[d] = f2h(n2 < 128 ? muw[n2 * 256 + kk] : lvw[(n2 - 128) * 256 + kk]);
  }
}

// ---------------- K1: conv1 batch stats (biasless: BN cancels conv bias) ----------------
__global__ __launch_bounds__(256) void k_stats1(const float* __restrict__ x,
    const float* __restrict__ w1, float* __restrict__ ws) {
  __shared__ float xbs[4][96];
  int tid = threadIdx.x, wv = tid >> 6, lane = tid & 63;
  int c = lane >> 2, nsub = lane & 3;
  float wr[9];
#pragma unroll
  for (int k = 0; k < 9; ++k) wr[k] = w1[c * 9 + k];
  float s = 0.f, ss = 0.f;
  float* xsp = xbs[wv];
  for (int i = lane; i < 96; i += 64) xsp[i] = 0.f;
  for (int it = 0; it < 16; ++it) {
    int b = blockIdx.x * 64 + wv * 16 + it;
    __syncthreads();
    if (lane < 56) xsp[((lane >> 3) + 1) * 10 + (lane & 7) + 1] = x[(size_t)b * NPOS + lane];
    __syncthreads();
#pragma unroll
    for (int i = 0; i < 14; ++i) {
      int n = nsub * 14 + i;
      int base = (n >> 3) * 10 + (n & 7);
      float acc = 0.f;
#pragma unroll
      for (int ky = 0; ky < 3; ++ky)
#pragma unroll
        for (int kx = 0; kx < 3; ++kx)
          acc += wr[ky * 3 + kx] * xsp[base + ky * 10 + kx];
      s += acc; ss += acc * acc;
    }
  }
  s += __shfl_xor(s, 1);  s += __shfl_xor(s, 2);
  ss += __shfl_xor(ss, 1); ss += __shfl_xor(ss, 2);
  if ((lane & 3) == 0) {
    atomicAdd(&ws[WS_SUM1 + c], s);
    atomicAdd(&ws[WS_SSQ1 + c], ss);
  }
}

// ---------------- finalize BN stats -> scale/shift ----------------
__global__ void k_finalize(const float* __restrict__ bnw, const float* __restrict__ bnb,
    float* __restrict__ ws, int nc, int so, int qo, int ao, int dof) {
  int c = threadIdx.x;
  if (c < nc) {
    float mean = ws[so + c] / CNT1;
    float var = ws[qo + c] / CNT1 - mean * mean;
    float a = bnw[c] * rsqrtf(var + 1e-5f);
    ws[ao + c] = a;
    ws[dof + c] = bnb[c] - a * mean;
  }
}

// ---------------- K2: conv1 + conv2(MFMA) -> y2 (f16) + bn2 stats ----------------
__global__ __launch_bounds__(256) void k_conv(const float* __restrict__ x,
    const float* __restrict__ w1, float* __restrict__ ws) {
  __shared__ ushort h1T[4][112 * 32];   // per-wave [112 padded-pos][32 halves (c1 in 0..15)]
  __shared__ ushort y2l[4][64 * 32];    // per-wave [64 pos][32 c2] f16
  __shared__ float xs4[4][96];
  __shared__ float sb[32], ssb[32];
  const ushort* w2r = (const ushort*)(ws + WS_W2R);
  ushort* y2h = (ushort*)(ws + WS_Y2H);
  int tid = threadIdx.x, wv = tid >> 6, lane = tid & 63;
  int lr = lane & 15, lk = lane >> 4;
  if (tid < 32) { sb[tid] = 0.f; ssb[tid] = 0.f; }
  ushort* h1 = h1T[wv];
  ushort* yl = y2l[wv];
  float* xsp = xs4[wv];
  for (int i = lane; i < 1792; i += 64) ((uint*)h1)[i] = 0;
  for (int i = lane; i < 96; i += 64) xsp[i] = 0.f;
  // A-fragments of conv2 weights (constant per kernel)
  f16x8 afr[2][5];
#pragma unroll
  for (int mi = 0; mi < 2; ++mi)
#pragma unroll
    for (int s2 = 0; s2 < 5; ++s2)
      afr[mi][s2] = *(const f16x8*)(w2r + (mi * 16 + lr) * 160 + s2 * 32 + lk * 8);
  // conv1 setup
  int c1l = lane >> 2, nsub = lane & 3;
  float wr[9];
#pragma unroll
  for (int k = 0; k < 9; ++k) wr[k] = w1[c1l * 9 + k];
  float a1 = ws[WS_A1 + c1l], d1 = ws[WS_D1 + c1l];
  // B-frag geometry
  int hi = lk >> 1, lo = lk & 1;
  int base4[4];
#pragma unroll
  for (int ni = 0; ni < 4; ++ni) {
    int n = lr + 16 * ni;
    base4[ni] = (n < 56) ? (n >> 3) * 10 + (n & 7) : 88;  // >=56 -> all-zero rows
  }
  const int dA_[5] = {0, 2, 11, 20, 22};
  const int dB_[5] = {1, 10, 12, 21, 0};
  float s8[8], ss8[8];
#pragma unroll
  for (int i = 0; i < 8; ++i) { s8[i] = 0.f; ss8[i] = 0.f; }
  __syncthreads();

  for (int r8 = 0; r8 < 8; ++r8) {
    int b = blockIdx.x * 32 + wv * 8 + r8;
    if (lane < 56) xsp[((lane >> 3) + 1) * 10 + (lane & 7) + 1] = x[(size_t)b * NPOS + lane];
    // conv1 + bn1 + relu -> h1T (wave-private, LDS ops in-order within wave)
#pragma unroll
    for (int i = 0; i < 14; ++i) {
      int n = nsub * 14 + i;
      int base = (n >> 3) * 10 + (n & 7);
      float acc = 0.f;
#pragma unroll
      for (int ky = 0; ky < 3; ++ky)
#pragma unroll
        for (int kx = 0; kx < 3; ++kx)
          acc += wr[ky * 3 + kx] * xsp[base + ky * 10 + kx];
      h1[(base + 11) * 32 + c1l] = f2h(fmaxf(acc * a1 + d1, 0.f));
    }
    // conv2 via MFMA: y2[c2][pos] = sum_k w2r[c2][k] * h1shift[k][pos]
    f32x4 acc2[2][4];
#pragma unroll
    for (int mi = 0; mi < 2; ++mi)
#pragma unroll
      for (int ni = 0; ni < 4; ++ni) { f32x4 z = {0.f, 0.f, 0.f, 0.f}; acc2[mi][ni] = z; }
#pragma unroll
    for (int s2 = 0; s2 < 5; ++s2) {
      f16x8 bf[4];
#pragma unroll
      for (int ni = 0; ni < 4; ++ni) {
        int row;
        if (s2 == 4) row = hi ? 104 : (base4[ni] + 22);
        else row = base4[ni] + (hi ? dB_[s2] : dA_[s2]);
        bf[ni] = *(const f16x8*)(h1 + row * 32 + lo * 8);
      }
#pragma unroll
      for (int mi = 0; mi < 2; ++mi)
#pragma unroll
        for (int ni = 0; ni < 4; ++ni)
          acc2[mi][ni] = __builtin_amdgcn_mfma_f32_16x16x32_f16(afr[mi][s2], bf[ni], acc2[mi][ni], 0, 0, 0);
    }
    // stats + pack to y2l [pos][c2]
#pragma unroll
    for (int mi = 0; mi < 2; ++mi)
#pragma unroll
      for (int ni = 0; ni < 4; ++ni) {
        f32x4 v = acc2[mi][ni];
        int pos = lr + 16 * ni;
        s8[mi * 4 + 0] += v[0]; ss8[mi * 4 + 0] += v[0] * v[0];
        s8[mi * 4 + 1] += v[1]; ss8[mi * 4 + 1] += v[1] * v[1];
        s8[mi * 4 + 2] += v[2]; ss8[mi * 4 + 2] += v[2] * v[2];
        s8[mi * 4 + 3] += v[3]; ss8[mi * 4 + 3] += v[3] * v[3];
        uint p01 = (uint)f2h(v[0]) | ((uint)f2h(v[1]) << 16);
        uint p23 = (uint)f2h(v[2]) | ((uint)f2h(v[3]) << 16);
        ((uint*)yl)[pos * 16 + lk * 2 + 8 * mi] = p01;
        ((uint*)yl)[pos * 16 + lk * 2 + 8 * mi + 1] = p23;
      }
    // copy first 56 rows -> global
    uint4* dst = (uint4*)y2h + (size_t)b * 224;
    for (int i = lane; i < 224; i += 64) dst[i] = ((const uint4*)yl)[i];
  }
  // reduce stats over the 16 pos-col lanes
#pragma unroll
  for (int i = 0; i < 8; ++i) {
    s8[i] += __shfl_xor(s8[i], 1);  s8[i] += __shfl_xor(s8[i], 2);
    s8[i] += __shfl_xor(s8[i], 4);  s8[i] += __shfl_xor(s8[i], 8);
    ss8[i] += __shfl_xor(ss8[i], 1); ss8[i] += __shfl_xor(ss8[i], 2);
    ss8[i] += __shfl_xor(ss8[i], 4); ss8[i] += __shfl_xor(ss8[i], 8);
  }
  if (lr == 0) {
#pragma unroll
    for (int i = 0; i < 8; ++i) {
      int c2 = lk * 4 + (i & 3) + 16 * (i >> 2);
      atomicAdd(&sb[c2], s8[i]);
      atomicAdd(&ssb[c2], ss8[i]);
    }
  }
  __syncthreads();
  if (tid < 32) {
    atomicAdd(&ws[WS_SUM2 + tid], sb[tid]);
    atomicAdd(&ws[WS_SSQ2 + tid], ssb[tid]);
  }
}

// ---------------- K3: attention, fully MFMA (qk-proj, scores, gT, PV) ----------------
__global__ __launch_bounds__(256) void k_attn(
    const float* __restrict__ qw, const float* __restrict__ qb_,
    const float* __restrict__ kw, const float* __restrict__ kb_,
    const float* __restrict__ vb_, const float* __restrict__ gp,
    float* __restrict__ ws) {
  __shared__ ushort h2m[4][2048];   // [pos][c2] f16, XOR-swizzled (row&3)<<4
  __shared__ ushort Pm[4][4096];    // [i][j] f16, XOR (row&7)<<4
  __shared__ ushort gm_[4][2048];   // [c][j] f16, XOR (row&7)<<4
  __shared__ float invl[4][64];
  const ushort* vwh = (const ushort*)(ws + WS_VWH);
  ushort* y2h = (ushort*)(ws + WS_Y2H);
  int tid = threadIdx.x, wv = tid >> 6, lane = tid & 63;
  int lr = lane & 15, lk = lane >> 4;
  ushort* h2 = h2m[wv]; ushort* Pl = Pm[wv]; ushort* gl = gm_[wv];
  float* iv = invl[wv];
  for (int i = lane; i < 1024; i += 64) ((uint*)h2)[i] = 0;
  float gamma = gp[0];
  // hoisted: v-weight B-frags + biases
  f16x8 vwf[2];
  float vbv[2];
#pragma unroll
  for (int ni = 0; ni < 2; ++ni) {
    vwf[ni] = *(const f16x8*)(vwh + (lr + 16 * ni) * 32 + lk * 8);
    vbv[ni] = vb_[lr + 16 * ni];
  }
  // hoisted: qk projection A-frag: rows 0..3 = qw*log2e, 4..7 = kw, 8..15 = 0
  f16x8 qkwA;
  {
    float aw[8];
#pragma unroll
    for (int e = 0; e < 8; ++e) aw[e] = 0.f;
    if (lr < 4) {
#pragma unroll
      for (int e = 0; e < 8; ++e) aw[e] = qw[lr * 32 + lk * 8 + e] * LOG2E;
    } else if (lr < 8) {
#pragma unroll
      for (int e = 0; e < 8; ++e) aw[e] = kw[(lr - 4) * 32 + lk * 8 + e];
    }
    uint4 wq;
    wq.x = pk2(aw[0], aw[1]); wq.y = pk2(aw[2], aw[3]);
    wq.z = pk2(aw[4], aw[5]); wq.w = pk2(aw[6], aw[7]);
    qkwA = __builtin_bit_cast(f16x8, wq);
  }
  // hoisted: per-lane o-bias for projection output rows o = lk*4+r
  f32x4 biasv;
#pragma unroll
  for (int r = 0; r < 4; ++r) {
    int o = lk * 4 + r;
    biasv[r] = (o < 4) ? qb_[o] * LOG2E : ((o < 8) ? kb_[o - 4] : 0.f);
  }
  f32x4 zz = {0.f, 0.f, 0.f, 0.f};

  for (int r8 = 0; r8 < 8; ++r8) {
    int b = blockIdx.x * 32 + wv * 8 + r8;
    // ---- stage 0: load y2 row, BN+ReLU, store h2 to LDS ----
    if (lane < 56) {
      const uint4* src = (const uint4*)y2h + (size_t)b * 224 + lane * 4;
      uint4 rows[4];
#pragma unroll
      for (int g = 0; g < 4; ++g) rows[g] = src[g];
#pragma unroll
      for (int g = 0; g < 4; ++g) {
        float h0_ = fmaxf(ws[WS_A2 + g * 8 + 0] * h2f(((const ushort*)&rows[g])[0]) + ws[WS_D2 + g * 8 + 0], 0.f);
        float h1_ = fmaxf(ws[WS_A2 + g * 8 + 1] * h2f(((const ushort*)&rows[g])[1]) + ws[WS_D2 + g * 8 + 1], 0.f);
        float h2_ = fmaxf(ws[WS_A2 + g * 8 + 2] * h2f(((const ushort*)&rows[g])[2]) + ws[WS_D2 + g * 8 + 2], 0.f);
        float h3_ = fmaxf(ws[WS_A2 + g * 8 + 3] * h2f(((const ushort*)&rows[g])[3]) + ws[WS_D2 + g * 8 + 3], 0.f);
        float h4_ = fmaxf(ws[WS_A2 + g * 8 + 4] * h2f(((const ushort*)&rows[g])[4]) + ws[WS_D2 + g * 8 + 4], 0.f);
        float h5_ = fmaxf(ws[WS_A2 + g * 8 + 5] * h2f(((const ushort*)&rows[g])[5]) + ws[WS_D2 + g * 8 + 5], 0.f);
        float h6_ = fmaxf(ws[WS_A2 + g * 8 + 6] * h2f(((const ushort*)&rows[g])[6]) + ws[WS_D2 + g * 8 + 6], 0.f);
        float h7_ = fmaxf(ws[WS_A2 + g * 8 + 7] * h2f(((const ushort*)&rows[g])[7]) + ws[WS_D2 + g * 8 + 7], 0.f);
        uint u0 = pk2(h0_, h1_), u1 = pk2(h2_, h3_), u2 = pk2(h4_, h5_), u3 = pk2(h6_, h7_);
        *(uint*)((char*)h2 + ((lane * 64 + (g * 4 + 0) * 4) ^ ((lane & 3) << 4))) = u0;
        *(uint*)((char*)h2 + ((lane * 64 + (g * 4 + 1) * 4) ^ ((lane & 3) << 4))) = u1;
        *(uint*)((char*)h2 + ((lane * 64 + (g * 4 + 2) * 4) ^ ((lane & 3) << 4))) = u2;
        *(uint*)((char*)h2 + ((lane * 64 + (g * 4 + 3) * 4) ^ ((lane & 3) << 4))) = u3;
      }
    }
    // ---- stage 1: QK^T = qkw @ h2^T via MFMA (4 tiles over pos) ----
    f32x4 vqk[4];
#pragma unroll
    for (int ni = 0; ni < 4; ++ni) {
      int pos = ni * 16 + lr;
      f16x8 hb2 = *(const f16x8*)((const char*)h2 + ((pos * 64 + lk * 16) ^ ((pos & 3) << 4)));
      f32x4 a = __builtin_amdgcn_mfma_f32_16x16x32_f16(qkwA, hb2, zz, 0, 0, 0);
      a[0] += biasv[0]; a[1] += biasv[1]; a[2] += biasv[2]; a[3] += biasv[3];
      vqk[ni] = a;
    }
    // ---- build score-MFMA fragments via shuffles ----
    // qfr[t]: B-operand, col i = t*16+lr, k 0..3 = q (lk==0 chunk only)
    // kfr[t]: A-operand, row j = t*16+lr, k 0..3 = k
    f16x8 qfr[4], kfr[4];
#pragma unroll
    for (int t = 0; t < 4; ++t) {
      float q0 = __shfl(vqk[t][0], lr),      q1 = __shfl(vqk[t][1], lr);
      float q2 = __shfl(vqk[t][2], lr),      q3 = __shfl(vqk[t][3], lr);
      float k0 = __shfl(vqk[t][0], 16 + lr), k1 = __shfl(vqk[t][1], 16 + lr);
      float k2 = __shfl(vqk[t][2], 16 + lr), k3 = __shfl(vqk[t][3], 16 + lr);
      uint4 uq = {0u, 0u, 0u, 0u}, uk = {0u, 0u, 0u, 0u};
      if (lk == 0) {
        uq.x = pk2(q0, q1); uq.y = pk2(q2, q3);
        uk.x = pk2(k0, k1); uk.y = pk2(k2, k3);
      }
      qfr[t] = __builtin_bit_cast(f16x8, uq);
      kfr[t] = __builtin_bit_cast(f16x8, uk);
    }
    // ---- scores: S^T[j][i] via 16 MFMAs ----
    f32x4 sac[4][4];
#pragma unroll
    for (int mi = 0; mi < 4; ++mi)
#pragma unroll
      for (int ni = 0; ni < 4; ++ni)
        sac[mi][ni] = __builtin_amdgcn_mfma_f32_16x16x32_f16(kfr[mi], qfr[ni], zz, 0, 0, 0);
    // ---- softmax per i-row (exp2 domain), masked j>=56, write P ----
#pragma unroll
    for (int ni = 0; ni < 4; ++ni) {
      float mx = -1e30f;
#pragma unroll
      for (int mi = 0; mi < 3; ++mi)
#pragma unroll
        for (int r = 0; r < 4; ++r) mx = fmaxf(mx, sac[mi][ni][r]);
      {
        float m3 = fmaxf(fmaxf(sac[3][ni][0], sac[3][ni][1]), fmaxf(sac[3][ni][2], sac[3][ni][3]));
        mx = fmaxf(mx, (lk < 2) ? m3 : -1e30f);
      }
      mx = fmaxf(mx, __shfl_xor(mx, 16));
      mx = fmaxf(mx, __shfl_xor(mx, 32));
      float den = 0.f;
      float ev[4][4];
#pragma unroll
      for (int mi = 0; mi < 4; ++mi)
#pragma unroll
        for (int r = 0; r < 4; ++r) {
          float e = __builtin_amdgcn_exp2f(sac[mi][ni][r] - mx);
          if (mi == 3) e = (lk < 2) ? e : 0.f;
          ev[mi][r] = e;
          den += e;
        }
      den += __shfl_xor(den, 16);
      den += __shfl_xor(den, 32);
      if (lk == 0) iv[ni * 16 + lr] = 1.f / den;
      int i = ni * 16 + lr;
#pragma unroll
      for (int mi = 0; mi < 4; ++mi) {
        uint2 pp;
        pp.x = pk2(ev[mi][0], ev[mi][1]);
        pp.y = pk2(ev[mi][2], ev[mi][3]);
        *(uint2*)((char*)Pl + ((i * 128 + mi * 32 + lk * 8) ^ ((lr & 7) << 4))) = pp;
      }
    }
    // ---- gT = h2 @ vw^T : [64 j][32 c] ----
    f32x4 ga[4][2];
#pragma unroll
    for (int mi = 0; mi < 4; ++mi) {
      int rw = lr + 16 * mi;
      f16x8 af = *(const f16x8*)((const char*)h2 + ((rw * 64 + lk * 16) ^ ((rw & 3) << 4)));
#pragma unroll
      for (int ni = 0; ni < 2; ++ni)
        ga[mi][ni] = __builtin_amdgcn_mfma_f32_16x16x32_f16(af, vwf[ni], zz, 0, 0, 0);
    }
#pragma unroll
    for (int mi = 0; mi < 4; ++mi)
#pragma unroll
      for (int ni = 0; ni < 2; ++ni) {
        f32x4 v = ga[mi][ni];
        int c = lr + 16 * ni;
        int jb2 = (lk * 4 + 16 * mi) * 2;
        uint p01 = pk2(v[0], v[1]);
        uint p23 = pk2(v[2], v[3]);
        *(uint*)((char*)gl + ((c * 128 + jb2) ^ ((c & 7) << 4))) = p01;
        *(uint*)((char*)gl + ((c * 128 + jb2 + 4) ^ ((c & 7) << 4))) = p23;
      }
    // ---- out = P @ gT : [64 i][32 c] ----
    f32x4 oa[4][2];
#pragma unroll
    for (int mi = 0; mi < 4; ++mi)
#pragma unroll
      for (int ni = 0; ni < 2; ++ni) oa[mi][ni] = zz;
#pragma unroll
    for (int ks = 0; ks < 2; ++ks) {
      f16x8 bfv[2];
#pragma unroll
      for (int ni = 0; ni < 2; ++ni) {
        int c = lr + 16 * ni;
        bfv[ni] = *(const f16x8*)((const char*)gl + ((c * 128 + ks * 64 + lk * 16) ^ ((c & 7) << 4)));
      }
#pragma unroll
      for (int mi = 0; mi < 4; ++mi) {
        int rw = lr + 16 * mi;
        f16x8 pf = *(const f16x8*)((const char*)Pl + ((rw * 128 + ks * 64 + lk * 16) ^ ((rw & 7) << 4)));
#pragma unroll
        for (int ni = 0; ni < 2; ++ni)
          oa[mi][ni] = __builtin_amdgcn_mfma_f32_16x16x32_f16(pf, bfv[ni], oa[mi][ni], 0, 0, 0);
      }
    }
    // ---- epilogue: h = gamma*(vb + inv*out) + h2, in-place into h2 LDS ----
#pragma unroll
    for (int mi = 0; mi < 4; ++mi) {
      float4 inv4 = *(const float4*)&iv[mi * 16 + lk * 4];
      float invr[4] = {inv4.x, inv4.y, inv4.z, inv4.w};
#pragma unroll
      for (int ni = 0; ni < 2; ++ni) {
        f32x4 v = oa[mi][ni];
        int c = lr + 16 * ni;
#pragma unroll
        for (int r = 0; r < 4; ++r) {
          int i = mi * 16 + lk * 4 + r;
          if (i < 56) {
            char* hp = (char*)h2 + ((i * 64 + c * 2) ^ ((i & 3) << 4));
            float h2v = h2f(*(ushort*)hp);
            *(ushort*)hp = f2h(gamma * (vbv[ni] + invr[r] * v[r]) + h2v);
          }
        }
      }
    }
    // ---- copy h rows 0..55 -> global (unswizzle) ----
    uint4* dst = (uint4*)y2h + (size_t)b * 224;
    for (int i2 = lane; i2 < 224; i2 += 64) {
      int row = i2 >> 2, slot = i2 & 3;
      dst[i2] = *(const uint4*)((const char*)h2 + row * 64 + ((slot ^ (row & 3)) * 16));
    }
  }
}

// ---------------- K4: fc1 + heads via f16 MFMA ----------------
__global__ __launch_bounds__(256) void k_fc(
    const float* __restrict__ fc1b, const float* __restrict__ mub,
    const float* __restrict__ lvb, const float* __restrict__ ws,
    float* __restrict__ out) {
  __shared__ __align__(16) ushort At[64 * 64];
  __shared__ __align__(16) ushort Bt[256 * 64];
  __shared__ __align__(16) ushort Ft[64 * 256];
  const ushort* hbuf = (const ushort*)(ws + WS_Y2H);
  const ushort* w1bf = (const ushort*)(ws + WS_W1BF);
  const ushort* whd  = (const ushort*)(ws + WS_WHD);
  int tid = threadIdx.x, wv = tid >> 6, lane = tid & 63;
  int m0 = blockIdx.x * 64;
  int lr = lane & 15, lk = lane >> 4;

  f32x4 acc[4][4];
#pragma unroll
  for (int mi = 0; mi < 4; ++mi)
#pragma unroll
    for (int ni = 0; ni < 4; ++ni) { f32x4 z = {0.f, 0.f, 0.f, 0.f}; acc[mi][ni] = z; }

  int arow = tid >> 2, ac4 = tid & 3;
  for (int kk = 0; kk < 1792; kk += 64) {
#pragma unroll
    for (int i = 0; i < 2; ++i) {
      int ch = ac4 * 2 + i;
      uint4 av = *(const uint4*)&hbuf[(size_t)(m0 + arow) * 1792 + kk + ch * 8];
      *(uint4*)&At[arow * 64 + ((ch ^ (arow & 7)) * 8)] = av;
    }
    {
      const ushort* src = &w1bf[tid * 1792 + kk];
#pragma unroll
      for (int i = 0; i < 8; ++i) {
        uint4 bv = *(const uint4*)&src[i * 8];
        *(uint4*)&Bt[tid * 64 + ((i ^ (tid & 7)) * 8)] = bv;
      }
    }
    __syncthreads();
#pragma unroll
    for (int t2 = 0; t2 < 2; ++t2) {
      f16x8 af[4], bfr[4];
#pragma unroll
      for (int mi = 0; mi < 4; ++mi) {
        int rr = mi * 16 + lr;
        int ch = (t2 * 4 + lk) ^ (rr & 7);
        af[mi] = *(const f16x8*)&At[rr * 64 + ch * 8];
      }
#pragma unroll
      for (int ni = 0; ni < 4; ++ni) {
        int rr = wv * 64 + ni * 16 + lr;
        int ch = (t2 * 4 + lk) ^ (rr & 7);
        bfr[ni] = *(const f16x8*)&Bt[rr * 64 + ch * 8];
      }
#pragma unroll
      for (int mi = 0; mi < 4; ++mi)
#pragma unroll
        for (int ni = 0; ni < 4; ++ni)
          acc[mi][ni] = __builtin_amdgcn_mfma_f32_16x16x32_f16(af[mi], bfr[ni], acc[mi][ni], 0, 0, 0);
    }
    __syncthreads();
  }
#pragma unroll
  for (int ni = 0; ni < 4; ++ni) {
    int n = wv * 64 + ni * 16 + lr;
    float bj = fc1b[n];
    int lc = n >> 3;
    int nl = n & 7;
#pragma unroll
    for (int mi = 0; mi < 4; ++mi) {
      f32x4 v = acc[mi][ni];
#pragma unroll
      for (int r = 0; r < 4; ++r) {
        int m = mi * 16 + lk * 4 + r;
        int chs = (lc & ~7) | ((lc & 7) ^ (m & 7));
        Ft[m * 256 + chs * 8 + nl] = f2h(fmaxf(v[r] + bj, 0.f));
      }
    }
  }
  __syncthreads();
  f32x4 acc2[4][4];
#pragma unroll
  for (int mi = 0; mi < 4; ++mi)
#pragma unroll
    for (int ni = 0; ni < 4; ++ni) { f32x4 z = {0.f, 0.f, 0.f, 0.f}; acc2[mi][ni] = z; }
  for (int kk2 = 0; kk2 < 256; kk2 += 64) {
    const ushort* src = &whd[tid * 256 + kk2];
#pragma unroll
    for (int i = 0; i < 8; ++i) {
      uint4 bv = *(const uint4*)&src[i * 8];
      *(uint4*)&Bt[tid * 64 + ((i ^ (tid & 7)) * 8)] = bv;
    }
    __syncthreads();
#pragma unroll
    for (int t2 = 0; t2 < 2; ++t2) {
      f16x8 af[4], bfr[4];
#pragma unroll
      for (int mi = 0; mi < 4; ++mi) {
        int m = mi * 16 + lr;
        int lc = (kk2 >> 3) + t2 * 4 + lk;
        int chs = (lc & ~7) | ((lc & 7) ^ (m & 7));
        af[mi] = *(const f16x8*)&Ft[m * 256 + chs * 8];
      }
#pragma unroll
      for (int ni = 0; ni < 4; ++ni) {
        int rr = wv * 64 + ni * 16 + lr;
        int ch = (t2 * 4 + lk) ^ (rr & 7);
        bfr[ni] = *(const f16x8*)&Bt[rr * 64 + ch * 8];
      }
#pragma unroll
      for (int mi = 0; mi < 4; ++mi)
#pragma unroll
        for (int ni = 0; ni < 4; ++ni)
          acc2[mi][ni] = __builtin_amdgcn_mfma_f32_16x16x32_f16(af[mi], bfr[ni], acc2[mi][ni], 0, 0, 0);
    }
    __syncthreads();
  }
#pragma unroll
  for (int ni = 0; ni < 4; ++ni) {
    int n2 = wv * 64 + ni * 16 + lr;
    int isLv = (n2 >= 128);
    float bias2 = isLv ? lvb[n2 - 128] : mub[n2];
    size_t obase = isLv ? ((size_t)BTOT * 128 + (n2 - 128)) : (size_t)n2;
#pragma unroll
    for (int mi = 0; mi < 4; ++mi) {
      f32x4 v = acc2[mi][ni];
#pragma unroll
      for (int r = 0; r < 4; ++r) {
        int m = m0 + mi * 16 + lk * 4 + r;
        out[obase + (size_t)m * 128] = v[r] + bias2;
      }
    }
  }
}

extern "C" void kernel_launch(void* const* d_in, const int* in_sizes, int n_in,
                              void* d_out, int out_size, void* d_ws, size_t ws_size,
                              hipStream_t stream) {
  const float* x    = (const float*)d_in[0];
  const float* c1w  = (const float*)d_in[1];
  const float* bn1w = (const float*)d_in[3];
  const float* bn1b = (const float*)d_in[4];
  const float* c2w  = (const float*)d_in[5];
  const float* bn2w = (const float*)d_in[7];
  const float* bn2b = (const float*)d_in[8];
  const float* qw   = (const float*)d_in[9];
  const float* qb   = (const float*)d_in[10];
  const float* kw   = (const float*)d_in[11];
  const float* kb   = (const float*)d_in[12];
  const float* vw   = (const float*)d_in[13];
  const float* vb   = (const float*)d_in[14];
  const float* gm   = (const float*)d_in[15];
  const float* fw   = (const float*)d_in[16];
  const float* fb   = (const float*)d_in[17];
  const float* muw  = (const float*)d_in[18];
  const float* mub  = (const float*)d_in[19];
  const float* lvw  = (const float*)d_in[20];
  const float* lvb  = (const float*)d_in[21];
  float* ws = (float*)d_ws;
  float* out = (float*)d_out;

  hipMemsetAsync(d_ws, 0, 96 * sizeof(float), stream);
  hipLaunchKernelGGL(k_pack, dim3(1024), dim3(256), 0, stream, c2w, vw, fw, muw, lvw, ws);
  hipLaunchKernelGGL(k_stats1, dim3(512), dim3(256), 0, stream, x, c1w, ws);
  hipLaunchKernelGGL(k_finalize, dim3(1), dim3(64), 0, stream, bn1w, bn1b, ws,
                     16, WS_SUM1, WS_SSQ1, WS_A1, WS_D1);
  hipLaunchKernelGGL(k_conv, dim3(1024), dim3(256), 0, stream, x, c1w, ws);
  hipLaunchKernelGGL(k_finalize, dim3(1), dim3(64), 0, stream, bn2w, bn2b, ws,
                     32, WS_SUM2, WS_SSQ2, WS_A2, WS_D2);
  hipLaunchKernelGGL(k_attn, dim3(1024), dim3(256), 0, stream,
                     qw, qb, kw, kb, vb, gm, ws);
  hipLaunchKernelGGL(k_fc, dim3(512), dim3(256), 0, stream, fb, mub, lvb, ws, out);
}